// Round 1
// baseline (1186.646 us; speedup 1.0000x reference)
//
#include <hip/hip_runtime.h>
#include <hip/hip_cooperative_groups.h>

namespace cg = cooperative_groups;

// ---------------------------------------------------------------------------
// TAGCN node regression: 3 TAGConv layers (K=4) + linear head, fp32 math.
// CSR-by-dst built once per launch (rank from degree atomic; fill atomic-free).
// fp16 inter-dispatch tensors, 4B packed edges [norm15|src17] (R10).
// R12: persistent cooperative kernel for layers 2+3 (wave-private t-tile).
// R13: degcount atomics were memory-side (device-scope coherence tax):
// WRITE_SIZE 115.5MB ~= 3.2M atomics x 32B, 19.5 Gops/s. Privatize pack[]
// per XCD (s_getreg XCC_ID) + workgroup-scope atomic -> XCD-local L2 RMW.
// scan combines 8 replicas and emits per-(node,xcd) base offsets (ushort x8);
// rank packs [xcd:16|local_rank:16]; fill adds base8[d][xcd].
// ---------------------------------------------------------------------------

typedef unsigned long long u64;
typedef unsigned int u32;

__device__ __forceinline__ int xcc_id() {
  int x;
  asm volatile("s_getreg_b32 %0, hwreg(HW_REG_XCC_ID)" : "=s"(x));
  return x & 7;
}

__device__ __forceinline__ float h2f(unsigned short u) {
  _Float16 h;
  __builtin_memcpy(&h, &u, 2);
  return (float)h;
}
__device__ __forceinline__ unsigned short f2h(float f) {
  _Float16 h = (_Float16)f;  // RNE
  unsigned short u;
  __builtin_memcpy(&u, &h, 2);
  return u;
}
__device__ __forceinline__ ushort4 pack_h(float4 v) {
  ushort4 r;
  r.x = f2h(v.x); r.y = f2h(v.y); r.z = f2h(v.z); r.w = f2h(v.w);
  return r;
}
__device__ __forceinline__ float4 unpack_h(ushort4 u) {
  return make_float4(h2f(u.x), h2f(u.y), h2f(u.z), h2f(u.w));
}
// packed edge: [norm15 | src17]
__device__ __forceinline__ void dec_ep(u32 u, int& s, float& w) {
  s = (int)(u & 0x1FFFFu);
  w = h2f((unsigned short)(u >> 17));
}

// one 64-bit L2-local atomic per edge into the XCD-private replica:
// [count:16 | sum_w Q16.32 fixed point:48]; + fused x->fp16 convert.
// rank[e] = [xcd:16 | local_rank:16].
__global__ void degcount_k(const int* __restrict__ dst, const float* __restrict__ w,
                           u64* __restrict__ pack, int* __restrict__ rank, int E,
                           const float4* __restrict__ x4, ushort4* __restrict__ xh, int n4,
                           int N) {
  int e = blockIdx.x * blockDim.x + threadIdx.x;
  if (e < n4) xh[e] = pack_h(x4[e]);
  if (e >= E) return;
  int xcd = xcc_id();
  int d = dst[e];
  u64 v = ((u64)1 << 48) | (u64)((double)w[e] * 4294967296.0);
  // workgroup scope: no cross-XCD coherence bits -> RMW stays in this XCD's L2.
  // Correct because replica (xcd*N+d) is only ever touched from this XCD.
  u64 old = __hip_atomic_fetch_add(&pack[(size_t)xcd * N + d], v,
                                   __ATOMIC_RELAXED, __HIP_MEMORY_SCOPE_WORKGROUP);
  rank[e] = (xcd << 16) | (int)(old >> 48);
}

// scan (256/block) fused with 8-replica combine -> deg, dinv, base8 offsets
__global__ void scan_blocks(const u64* __restrict__ pack, float* __restrict__ dinv,
                            int* __restrict__ ptr, int* __restrict__ bsum,
                            ushort* __restrict__ base8, int n) {
  __shared__ int s[256];
  int tid = threadIdx.x;
  int i = blockIdx.x * 256 + tid;
  int v = 0;
  if (i < n) {
    int cnt = 0;
    u64 wsum = 0;
    ushort bs[8];
#pragma unroll
    for (int x = 0; x < 8; ++x) {
      u64 p = pack[(size_t)x * n + i];
      bs[x] = (ushort)cnt;
      cnt += (int)(p >> 48);
      wsum += p & 0xFFFFFFFFFFFFULL;
    }
    *(ushort4*)(base8 + (size_t)i * 8)     = make_ushort4(bs[0], bs[1], bs[2], bs[3]);
    *(ushort4*)(base8 + (size_t)i * 8 + 4) = make_ushort4(bs[4], bs[5], bs[6], bs[7]);
    v = cnt;
    float d = (float)((double)wsum * (1.0 / 4294967296.0));
    dinv[i] = (d > 0.f) ? rsqrtf(fmaxf(d, 1e-30f)) : 0.f;
  }
  s[tid] = v;
  __syncthreads();
#pragma unroll
  for (int off = 1; off < 256; off <<= 1) {
    int t = (tid >= off) ? s[tid - off] : 0;
    __syncthreads();
    s[tid] += t;
    __syncthreads();
  }
  if (i < n) ptr[i] = s[tid] - v;
  if (tid == 255) bsum[blockIdx.x] = s[255];
}

__global__ void scan_sums(int* __restrict__ bsum, int nb) {
  __shared__ int s[512];
  int tid = threadIdx.x;
  int v = (tid < nb) ? bsum[tid] : 0;
  s[tid] = v;
  __syncthreads();
#pragma unroll
  for (int off = 1; off < 512; off <<= 1) {
    int t = (tid >= off) ? s[tid - off] : 0;
    __syncthreads();
    s[tid] += t;
    __syncthreads();
  }
  if (tid < nb) bsum[tid] = s[tid] - v;
}

__global__ void scan_add(int* __restrict__ ptr, const int* __restrict__ bsum, int n, int E) {
  int i = blockIdx.x * blockDim.x + threadIdx.x;
  if (i < n) ptr[i] += bsum[i >> 8];
  if (i == 0) ptr[n] = E;
}

// scatter edges into CSR slots (atomic-free); payload = [norm15|src17] u32
__global__ void fill_k(const int* __restrict__ src, const int* __restrict__ dst,
                       const float* __restrict__ w, const float* __restrict__ dinv,
                       const int* __restrict__ ptr, const int* __restrict__ rank,
                       const ushort* __restrict__ base8,
                       u32* __restrict__ ep, int E) {
  int e = blockIdx.x * blockDim.x + threadIdx.x;
  if (e >= E) return;
  int s = src[e], d = dst[e];
  float nv = dinv[s] * w[e] * dinv[d];
  int r = rank[e];
  int pos = ptr[d] + (int)base8[(size_t)d * 8 + (r >> 16)] + (r & 0xFFFF);
  ep[pos] = ((u32)f2h(nv) << 17) | (u32)s;  // norm>=0 -> sign bit free
}

// gather t[f4] = sum_e w_e * fp16(hin[src_e][f4]); 2-edge unroll, 4B edges
template <int F4>
__device__ __forceinline__ float4 gather(const int* __restrict__ ptr, const u32* __restrict__ ep,
                                         const ushort4* __restrict__ hin, int node, int f4) {
  int e0 = ptr[node], e1 = ptr[node + 1];
  float4 a = make_float4(0.f, 0.f, 0.f, 0.f);
  int e = e0;
  if ((e & 1) && e < e1) {
    int s0; float w0; dec_ep(ep[e], s0, w0);
    ushort4 h = hin[(size_t)s0 * F4 + f4];
    a.x = fmaf(w0, h2f(h.x), a.x); a.y = fmaf(w0, h2f(h.y), a.y);
    a.z = fmaf(w0, h2f(h.z), a.z); a.w = fmaf(w0, h2f(h.w), a.w);
    ++e;
  }
  for (; e + 1 < e1; e += 2) {
    uint2 p = *(const uint2*)(ep + e);  // 2 edges, 8B aligned
    int s0, s1; float w0, w1;
    dec_ep(p.x, s0, w0);
    dec_ep(p.y, s1, w1);
    ushort4 h0 = hin[(size_t)s0 * F4 + f4];
    ushort4 h1 = hin[(size_t)s1 * F4 + f4];
    a.x = fmaf(w0, h2f(h0.x), a.x); a.y = fmaf(w0, h2f(h0.y), a.y);
    a.z = fmaf(w0, h2f(h0.z), a.z); a.w = fmaf(w0, h2f(h0.w), a.w);
    a.x = fmaf(w1, h2f(h1.x), a.x); a.y = fmaf(w1, h2f(h1.y), a.y);
    a.z = fmaf(w1, h2f(h1.z), a.z); a.w = fmaf(w1, h2f(h1.w), a.w);
  }
  if (e < e1) {
    int s0; float w0; dec_ep(ep[e], s0, w0);
    ushort4 h = hin[(size_t)s0 * F4 + f4];
    a.x = fmaf(w0, h2f(h.x), a.x); a.y = fmaf(w0, h2f(h.y), a.y);
    a.z = fmaf(w0, h2f(h.z), a.z); a.w = fmaf(w0, h2f(h.w), a.w);
  }
  return a;
}

// scalar-broadcast mm accumulate: a += t(slot ln) @ W  (R6's 28-VGPR shape).
// t element i of slot ln lives at word ln*64 + (((i>>2)^ln)<<2 | (i&3)).
// Tile rows are WAVE-PRIVATE (ln = tid>>4): same-wave LDS RAW needs no barrier.
__device__ __forceinline__ void mm_acc(const float* __restrict__ tl, const float4* __restrict__ Wl,
                                       int ln, int j4, float4& a) {
#pragma unroll 8
  for (int i = 0; i < 64; ++i) {
    float tv = tl[ln * 64 + ((((i >> 2) ^ ln) << 2) | (i & 3))];
    float4 wv = Wl[i * 16 + j4];
    a.x = fmaf(tv, wv.x, a.x); a.y = fmaf(tv, wv.y, a.y);
    a.z = fmaf(tv, wv.z, a.z); a.w = fmaf(tv, wv.w, a.w);
  }
}

// ---------- persistent cooperative kernel: layers 2+3 + head ----------
// Each block owns NC chunks of 16 nodes across all phases; acc in VGPRs.
// LDS = 16K W + 4K wave-private tile = 20480 B. Barriers only around Wl.
template <int NC>
__global__ __launch_bounds__(256) void mega_k(
    const int* __restrict__ ptr, const u32* __restrict__ ep,
    ushort4* __restrict__ hb0, ushort4* __restrict__ hb1, ushort4* __restrict__ hb2,
    const float* __restrict__ W2, const float* __restrict__ b2,
    const float* __restrict__ Wout, const float* __restrict__ bout,
    float* __restrict__ outv, int n) {
  cg::grid_group grid = cg::this_grid();
  __shared__ float4 Wl[1024];
  __shared__ float4 tl4[256];
  const float* tl = (const float*)tl4;
  const int tid = threadIdx.x, j4 = tid & 15, ln = tid >> 4;
  const int nb = (int)gridDim.x;
  float4 acc[NC];

  for (int L = 0; L < 2; ++L) {
    const float* WL = W2 + (size_t)L * 5 * 4096;
#pragma unroll
    for (int c = 0; c < NC; ++c) acc[c] = make_float4(0.f, 0.f, 0.f, 0.f);

    // ---- own-term pass: acc += h_in @ W0  (h_in = hb2 for both layers) ----
    {
      const float4* W04 = (const float4*)WL;
      for (int i = tid; i < 1024; i += 256) Wl[i] = W04[i];
      __syncthreads();  // Wl visible to all waves
#pragma unroll
      for (int c = 0; c < NC; ++c) {
        int node = (c * nb + (int)blockIdx.x) * 16 + ln;
        float4 own = make_float4(0.f, 0.f, 0.f, 0.f);
        if (node < n) own = unpack_h(hb2[(size_t)node * 16 + j4]);
        tl4[ln * 16 + (j4 ^ ln)] = own;   // wave-private row, no barrier
        mm_acc(tl, Wl, ln, j4, acc[c]);
      }
      __syncthreads();  // all waves done reading Wl(W0) before reload
    }

    // ---- k = 1..4 propagation phases ----
    for (int k = 1; k <= 4; ++k) {
      const ushort4* gsrc = (k == 1) ? hb2 : ((k == 3) ? hb1 : hb0);
      ushort4* gdst = (k == 2) ? hb1 : hb0;
      const bool last = (k == 4);
      const float4* Wk4 = (const float4*)(WL + (size_t)k * 4096);
      for (int i = tid; i < 1024; i += 256) Wl[i] = Wk4[i];
      __syncthreads();
#pragma unroll
      for (int c = 0; c < NC; ++c) {
        int node = (c * nb + (int)blockIdx.x) * 16 + ln;
        float4 t = make_float4(0.f, 0.f, 0.f, 0.f);
        if (node < n) {
          t = gather<16>(ptr, ep, gsrc, node, j4);
          if (!last) gdst[(size_t)node * 16 + j4] = pack_h(t);
        }
        tl4[ln * 16 + (j4 ^ ln)] = t;     // wave-private, no barrier
        mm_acc(tl, Wl, ln, j4, acc[c]);
      }
      if (last) {  // epilogue: bias + leaky -> layer output (L0) or head (L1)
        const float4* bias4 = (const float4*)(b2 + (size_t)L * 64);
#pragma unroll
        for (int c = 0; c < NC; ++c) {
          int node = (c * nb + (int)blockIdx.x) * 16 + ln;
          if (node >= n) continue;
          float4 a = acc[c];
          float4 b = bias4[j4];
          a.x += b.x; a.y += b.y; a.z += b.z; a.w += b.w;
          a.x = (a.x >= 0.f) ? a.x : 0.01f * a.x;
          a.y = (a.y >= 0.f) ? a.y : 0.01f * a.y;
          a.z = (a.z >= 0.f) ? a.z : 0.01f * a.z;
          a.w = (a.w >= 0.f) ? a.w : 0.01f * a.w;
          if (L == 0) {
            hb2[(size_t)node * 16 + j4] = pack_h(a);
          } else {
            float v = a.x * Wout[4 * j4] + a.y * Wout[4 * j4 + 1] +
                      a.z * Wout[4 * j4 + 2] + a.w * Wout[4 * j4 + 3];
            v += __shfl_down(v, 8, 16);
            v += __shfl_down(v, 4, 16);
            v += __shfl_down(v, 2, 16);
            v += __shfl_down(v, 1, 16);
            if (j4 == 0) outv[node] = v + bout[0];
          }
        }
      }
      if (!(L == 1 && k == 4)) {
        __threadfence();  // device-scope release of gdst/hb2 stores
        grid.sync();      // phase boundary (covers block sync for Wl reload)
      }
    }
  }
}

// ---------- fallback fused prop + matmul, F=64 (R10, fp16 acc) ----------
template <bool FIRST, bool LAST, bool HEAD>
__launch_bounds__(256)
__global__ void ptag64_k(const int* __restrict__ ptr, const u32* __restrict__ ep,
                         const ushort4* __restrict__ hin, ushort4* __restrict__ hout,
                         const float4* __restrict__ Wk4, const float4* __restrict__ W04,
                         ushort4* __restrict__ acch, const float4* __restrict__ bias4,
                         const float* __restrict__ Wout, const float* __restrict__ bout,
                         float* __restrict__ outv, int n) {
  __shared__ float4 Wl[1024];
  __shared__ float4 tl4[256];
  const float* tl = (const float*)tl4;
  int tid = threadIdx.x;
  for (int i = tid; i < 1024; i += 256) Wl[i] = Wk4[i];
  int gid = blockIdx.x * 256 + tid;
  int node = gid >> 4, j4 = gid & 15, ln = tid >> 4;

  float4 t = make_float4(0.f, 0.f, 0.f, 0.f);
  if (node < n) {
    t = gather<16>(ptr, ep, hin, node, j4);
    if (!LAST) hout[(size_t)node * 16 + j4] = pack_h(t);
  }
  tl4[ln * 16 + (j4 ^ ln)] = t;
  __syncthreads();

  float4 a = make_float4(0.f, 0.f, 0.f, 0.f);
  if (!FIRST && node < n) a = unpack_h(acch[(size_t)node * 16 + j4]);
  mm_acc(tl, Wl, ln, j4, a);
  if (FIRST) {
    __syncthreads();
    for (int i = tid; i < 1024; i += 256) Wl[i] = W04[i];
    float4 own = make_float4(0.f, 0.f, 0.f, 0.f);
    if (node < n) own = unpack_h(hin[(size_t)node * 16 + j4]);
    tl4[ln * 16 + (j4 ^ ln)] = own;
    __syncthreads();
    mm_acc(tl, Wl, ln, j4, a);
  }
  if (node >= n) return;

  if (LAST) {
    float4 b = bias4[j4];
    a.x += b.x; a.y += b.y; a.z += b.z; a.w += b.w;
    a.x = (a.x >= 0.f) ? a.x : 0.01f * a.x;
    a.y = (a.y >= 0.f) ? a.y : 0.01f * a.y;
    a.z = (a.z >= 0.f) ? a.z : 0.01f * a.z;
    a.w = (a.w >= 0.f) ? a.w : 0.01f * a.w;
    if (HEAD) {
      float v = a.x * Wout[4 * j4] + a.y * Wout[4 * j4 + 1] +
                a.z * Wout[4 * j4 + 2] + a.w * Wout[4 * j4 + 3];
      v += __shfl_down(v, 8, 16);
      v += __shfl_down(v, 4, 16);
      v += __shfl_down(v, 2, 16);
      v += __shfl_down(v, 1, 16);
      if (j4 == 0) outv[node] = v + bout[0];
    } else {
      hout[(size_t)node * 16 + j4] = pack_h(a);
    }
  } else {
    acch[(size_t)node * 16 + j4] = pack_h(a);
  }
}

// ---------- fused prop + matmul, layer 1: F_in=16 (4 lanes/node) ----------
template <bool FIRST, bool LAST>
__launch_bounds__(256)
__global__ void ptag16_k(const int* __restrict__ ptr, const u32* __restrict__ ep,
                         const ushort4* __restrict__ hin, ushort4* __restrict__ hout,
                         const float4* __restrict__ Wk4, const float4* __restrict__ W04,
                         ushort4* __restrict__ acch, const float4* __restrict__ bias4,
                         ushort4* __restrict__ outbuf, int n) {
  __shared__ float4 Wl[256];
  __shared__ float4 W0l[FIRST ? 256 : 1];
  __shared__ float4 tl4[64 * 5];
  const float* tl = (const float*)tl4;
  int tid = threadIdx.x;
  Wl[tid] = Wk4[tid];
  if (FIRST) W0l[tid] = W04[tid];
  int gid = blockIdx.x * 256 + tid;
  int node = gid >> 2, q = tid & 3, ln = tid >> 2;

  float4 t = make_float4(0.f, 0.f, 0.f, 0.f);
  if (node < n) {
    t = gather<4>(ptr, ep, hin, node, q);
    if (!LAST) hout[(size_t)node * 4 + q] = pack_h(t);
  }
  tl4[ln * 5 + q] = t;
  __syncthreads();

  float4 a[4];
#pragma unroll
  for (int c = 0; c < 4; ++c) a[c] = make_float4(0.f, 0.f, 0.f, 0.f);
  if (!FIRST && node < n) {
#pragma unroll
    for (int c = 0; c < 4; ++c) a[c] = unpack_h(acch[(size_t)node * 16 + 4 * q + c]);
  }
#pragma unroll 4
  for (int i = 0; i < 16; ++i) {
    float tv = tl[ln * 20 + i];
#pragma unroll
    for (int c = 0; c < 4; ++c) {
      float4 wv = Wl[i * 16 + 4 * q + c];
      a[c].x = fmaf(tv, wv.x, a[c].x); a[c].y = fmaf(tv, wv.y, a[c].y);
      a[c].z = fmaf(tv, wv.z, a[c].z); a[c].w = fmaf(tv, wv.w, a[c].w);
    }
  }
  if (FIRST) {
    __syncthreads();
    float4 own = make_float4(0.f, 0.f, 0.f, 0.f);
    if (node < n) own = unpack_h(hin[(size_t)node * 4 + q]);
    tl4[ln * 5 + q] = own;
    __syncthreads();
#pragma unroll 4
    for (int i = 0; i < 16; ++i) {
      float tv = tl[ln * 20 + i];
#pragma unroll
      for (int c = 0; c < 4; ++c) {
        float4 wv = W0l[i * 16 + 4 * q + c];
        a[c].x = fmaf(tv, wv.x, a[c].x); a[c].y = fmaf(tv, wv.y, a[c].y);
        a[c].z = fmaf(tv, wv.z, a[c].z); a[c].w = fmaf(tv, wv.w, a[c].w);
      }
    }
  }
  if (node >= n) return;

  if (LAST) {
#pragma unroll
    for (int c = 0; c < 4; ++c) {
      float4 b = bias4[4 * q + c];
      a[c].x += b.x; a[c].y += b.y; a[c].z += b.z; a[c].w += b.w;
      a[c].x = (a[c].x >= 0.f) ? a[c].x : 0.01f * a[c].x;
      a[c].y = (a[c].y >= 0.f) ? a[c].y : 0.01f * a[c].y;
      a[c].z = (a[c].z >= 0.f) ? a[c].z : 0.01f * a[c].z;
      a[c].w = (a[c].w >= 0.f) ? a[c].w : 0.01f * a[c].w;
      outbuf[(size_t)node * 16 + 4 * q + c] = pack_h(a[c]);
    }
  } else {
#pragma unroll
    for (int c = 0; c < 4; ++c) acch[(size_t)node * 16 + 4 * q + c] = pack_h(a[c]);
  }
}

extern "C" void kernel_launch(void* const* d_in, const int* in_sizes, int n_in,
                              void* d_out, int out_size, void* d_ws, size_t ws_size,
                              hipStream_t stream) {
  const float* x    = (const float*)d_in[0];
  const int*   ei   = (const int*)d_in[1];
  const float* ew   = (const float*)d_in[2];
  const float* W1   = (const float*)d_in[4];
  const float* b1   = (const float*)d_in[5];
  const float* W2   = (const float*)d_in[6];
  const float* b2   = (const float*)d_in[7];
  const float* Wout = (const float*)d_in[8];
  const float* bout = (const float*)d_in[9];
  float* out = (float*)d_out;

  const int N = in_sizes[0] / 16;
  const int E = in_sizes[2];
  const int* src = ei;
  const int* dst = ei + E;

  char* ws = (char*)d_ws;
  size_t off = 0;
  auto alloc = [&](size_t bytes) {
    char* p = ws + off;
    off = (off + bytes + 255) & ~(size_t)255;
    return p;
  };
  u64*     pack  = (u64*)alloc((size_t)N * 8 * 8);           // 8 XCD replicas
  float*   dinv  = (float*)alloc((size_t)N * 4);
  int*     ptr   = (int*)alloc(((size_t)N + 1) * 4);
  int*     bsum  = (int*)alloc(4096);
  ushort*  base8 = (ushort*)alloc((size_t)N * 8 * 2);        // per-(node,xcd) rank base
  int*     rank  = (int*)alloc((size_t)E * 4);
  u32*     ep    = (u32*)alloc((size_t)E * 4);               // packed 4B edges
  ushort4* xh    = (ushort4*)alloc((size_t)N * 16 * 2);      // N x 16 fp16
  ushort4* hb0   = (ushort4*)alloc((size_t)N * 64 * 2);      // t ping
  ushort4* hb1   = (ushort4*)alloc((size_t)N * 64 * 2);      // t pong
  ushort4* hb2   = (ushort4*)alloc((size_t)N * 64 * 2);      // layer outputs
  ushort4* acch  = (ushort4*)alloc((size_t)N * 64 * 2);      // fp16 acc (layer1/fallback)

  hipMemsetAsync(pack, 0, (size_t)N * 8 * 8, stream);

  int gE = (E + 255) / 256;
  int gN = (N + 255) / 256;
  degcount_k<<<gE, 256, 0, stream>>>(dst, ew, pack, rank, E, (const float4*)x, xh, N * 4, N);
  scan_blocks<<<gN, 256, 0, stream>>>(pack, dinv, ptr, bsum, base8, N);
  scan_sums<<<1, 512, 0, stream>>>(bsum, gN);
  scan_add<<<gN, 256, 0, stream>>>(ptr, bsum, N, E);
  fill_k<<<gE, 256, 0, stream>>>(src, dst, ew, dinv, ptr, rank, base8, ep, E);

  int g4  = (N * 4 + 255) / 256;   // layer-1 fused (4 lanes/node)
  int g16 = (N * 16 + 255) / 256;  // fallback F=64 fused

  auto W1k = [&](int k) { return (const float4*)(W1 + (size_t)k * 1024); };
  auto W2k = [&](int l, int k) { return (const float4*)(W2 + ((size_t)l * 5 + k) * 4096); };

  // ---- Layer 1 (16 -> 64): acc in acch, t ping-pong hb0/hb1, h1 -> hb2 ----
  ptag16_k<true,  false><<<g4, 256, 0, stream>>>(ptr, ep, xh,  hb0, W1k(1), W1k(0), acch, nullptr, nullptr, N);
  ptag16_k<false, false><<<g4, 256, 0, stream>>>(ptr, ep, hb0, hb1, W1k(2), nullptr, acch, nullptr, nullptr, N);
  ptag16_k<false, false><<<g4, 256, 0, stream>>>(ptr, ep, hb1, hb0, W1k(3), nullptr, acch, nullptr, nullptr, N);
  ptag16_k<false, true ><<<g4, 256, 0, stream>>>(ptr, ep, hb0, nullptr, W1k(4), nullptr, acch,
                                                 (const float4*)b1, hb2, N);

  // ---- Layers 2+3 + head: persistent cooperative kernel (occupancy-gated) ----
  int maxB4 = 0, maxB5 = 0, maxB7 = 0;
  (void)hipOccupancyMaxActiveBlocksPerMultiprocessor(&maxB4, mega_k<4>, 256, 0);
  (void)hipOccupancyMaxActiveBlocksPerMultiprocessor(&maxB5, mega_k<5>, 256, 0);
  (void)hipOccupancyMaxActiveBlocksPerMultiprocessor(&maxB7, mega_k<7>, 256, 0);
  void* fn = nullptr;
  int grid = 0;
  if ((long)maxB4 * 256 * 16 * 4 >= (long)N) {
    fn = (void*)mega_k<4>; grid = maxB4 * 256;
  } else if ((long)maxB5 * 256 * 16 * 5 >= (long)N) {
    fn = (void*)mega_k<5>; grid = maxB5 * 256;
  } else if ((long)maxB7 * 256 * 16 * 7 >= (long)N) {
    fn = (void*)mega_k<7>; grid = maxB7 * 256;
  }

  if (fn) {
    const int* ptrA = ptr; const u32* epA = ep;
    ushort4 *h0A = hb0, *h1A = hb1, *h2A = hb2;
    const float *W2A = W2, *b2A = b2, *WoA = Wout, *boA = bout;
    float* outA = out; int nA = N;
    void* args[] = {&ptrA, &epA, &h0A, &h1A, &h2A, &W2A, &b2A, &WoA, &boA, &outA, &nA};
    hipLaunchCooperativeKernel(fn, dim3(grid), dim3(256), args, 0, stream);
  } else {
    // fallback: R10's proven dispatch sequence
    ptag64_k<true,  false, false><<<g16, 256, 0, stream>>>(ptr, ep, hb2, hb0, W2k(0,1), W2k(0,0), acch,
                                                           nullptr, nullptr, nullptr, nullptr, N);
    ptag64_k<false, false, false><<<g16, 256, 0, stream>>>(ptr, ep, hb0, hb1, W2k(0,2), nullptr, acch,
                                                           nullptr, nullptr, nullptr, nullptr, N);
    ptag64_k<false, false, false><<<g16, 256, 0, stream>>>(ptr, ep, hb1, hb0, W2k(0,3), nullptr, acch,
                                                           nullptr, nullptr, nullptr, nullptr, N);
    ptag64_k<false, true,  false><<<g16, 256, 0, stream>>>(ptr, ep, hb0, hb2, W2k(0,4), nullptr, acch,
                                                           (const float4*)b2, nullptr, nullptr, nullptr, N);
    ptag64_k<true,  false, false><<<g16, 256, 0, stream>>>(ptr, ep, hb2, hb0, W2k(1,1), W2k(1,0), acch,
                                                           nullptr, nullptr, nullptr, nullptr, N);
    ptag64_k<false, false, false><<<g16, 256, 0, stream>>>(ptr, ep, hb0, hb1, W2k(1,2), nullptr, acch,
                                                           nullptr, nullptr, nullptr, nullptr, N);
    ptag64_k<false, false, false><<<g16, 256, 0, stream>>>(ptr, ep, hb1, hb0, W2k(1,3), nullptr, acch,
                                                           nullptr, nullptr, nullptr, nullptr, N);
    ptag64_k<false, true,  true ><<<g16, 256, 0, stream>>>(ptr, ep, hb0, nullptr, W2k(1,4), nullptr, acch,
                                                           (const float4*)(b2 + 64), Wout, bout, out, N);
  }
}

// Round 2
// 1089.606 us; speedup vs baseline: 1.0891x; 1.0891x over previous
//
#include <hip/hip_runtime.h>
#include <hip/hip_cooperative_groups.h>

namespace cg = cooperative_groups;

// ---------------------------------------------------------------------------
// TAGCN node regression: 3 TAGConv layers (K=4) + linear head, fp32 math.
// R14: ZERO-global-atomic CSR build. R13 proved the per-edge atomic executes
// memory-side regardless of scope (WRITE_SIZE identical 115.5MB, ~20Gops/s
// per-op cap). Replace degcount/fill with a deterministic two-level bucket
// sort: coarse hist by dst>>7 (LDS) -> exact (bucket,block) bases via global
// scan -> LDS-cursor scatter of 8B items [w_f32|dstlow7|src17] -> per-bucket
// LDS sort (128 bins) producing ptr/dinv + in-place reorder -> norm pack.
// w carried fp32 end-to-end; wsum fp32 (matches reference segment_sum).
// Downstream (ptag16 x4 + persistent cooperative mega_k) unchanged.
// ---------------------------------------------------------------------------

typedef unsigned long long u64;
typedef unsigned int u32;

__device__ __forceinline__ float h2f(unsigned short u) {
  _Float16 h;
  __builtin_memcpy(&h, &u, 2);
  return (float)h;
}
__device__ __forceinline__ unsigned short f2h(float f) {
  _Float16 h = (_Float16)f;  // RNE
  unsigned short u;
  __builtin_memcpy(&u, &h, 2);
  return u;
}
__device__ __forceinline__ ushort4 pack_h(float4 v) {
  ushort4 r;
  r.x = f2h(v.x); r.y = f2h(v.y); r.z = f2h(v.z); r.w = f2h(v.w);
  return r;
}
__device__ __forceinline__ float4 unpack_h(ushort4 u) {
  return make_float4(h2f(u.x), h2f(u.y), h2f(u.z), h2f(u.w));
}
// packed edge: [norm15 | src17]
__device__ __forceinline__ void dec_ep(u32 u, int& s, float& w) {
  s = (int)(u & 0x1FFFFu);
  w = h2f((unsigned short)(u >> 17));
}

// ---------------- atomic-free CSR build ----------------
// coarse bucket = dst >> 7 (128 nodes/bucket). NB <= 1024 (N <= 131072).
// item u64 = [0:8][w_f32:32][dst_low7:7][src:17]

// per-block LDS hist of dst>>7 -> H[bucket*NBLK + blk]; fused x->fp16
__global__ __launch_bounds__(256) void k_hist(const int* __restrict__ dst, u32* __restrict__ H,
                                              int E, int CH, int NB,
                                              const float4* __restrict__ x4,
                                              ushort4* __restrict__ xh, int n4) {
  __shared__ u32 hc[1024];
  int tid = threadIdx.x, blk = blockIdx.x, nblk = gridDim.x;
  for (int i = tid; i < 1024; i += 256) hc[i] = 0;
  for (int i = blk * 256 + tid; i < n4; i += nblk * 256) xh[i] = pack_h(x4[i]);
  __syncthreads();
  int e0 = blk * CH, e1 = min(E, e0 + CH);
  for (int e = e0 + tid; e < e1; e += 256) atomicAdd(&hc[((u32)dst[e]) >> 7], 1u);
  __syncthreads();
  for (int c = tid; c < NB; c += 256) H[(size_t)c * nblk + blk] = hc[c];
}

// exclusive scan of H (n = NB*256 entries), 256/block
__global__ void scanH_blocks(u32* __restrict__ H, u32* __restrict__ bsum, int n) {
  __shared__ u32 s[256];
  int tid = threadIdx.x;
  int i = blockIdx.x * 256 + tid;
  u32 v = (i < n) ? H[i] : 0;
  s[tid] = v;
  __syncthreads();
#pragma unroll
  for (int off = 1; off < 256; off <<= 1) {
    u32 t = (tid >= off) ? s[tid - off] : 0;
    __syncthreads();
    s[tid] += t;
    __syncthreads();
  }
  if (i < n) H[i] = s[tid] - v;
  if (tid == 255) bsum[blockIdx.x] = s[255];
}

__global__ void scanH_sums(u32* __restrict__ bsum, int nb) {
  __shared__ u32 s[1024];
  int tid = threadIdx.x;
  u32 v = (tid < nb) ? bsum[tid] : 0;
  s[tid] = v;
  __syncthreads();
#pragma unroll
  for (int off = 1; off < 1024; off <<= 1) {
    u32 t = (tid >= off) ? s[tid - off] : 0;
    __syncthreads();
    s[tid] += t;
    __syncthreads();
  }
  if (tid < nb) bsum[tid] = s[tid] - v;
}

__global__ void scanH_add(u32* __restrict__ H, const u32* __restrict__ bsum, int n) {
  int i = blockIdx.x * blockDim.x + threadIdx.x;
  if (i < n) H[i] += bsum[i >> 8];
}

// scatter edges into coarse-bucket regions via LDS cursors (no global atomics)
__global__ __launch_bounds__(256) void k_scatter(const int* __restrict__ src,
                                                 const int* __restrict__ dst,
                                                 const float* __restrict__ w,
                                                 const u32* __restrict__ H,
                                                 u64* __restrict__ sorted, int E, int CH, int NB) {
  __shared__ u32 cur[1024];
  int tid = threadIdx.x, blk = blockIdx.x, nblk = gridDim.x;
  for (int c = tid; c < NB; c += 256) cur[c] = H[(size_t)c * nblk + blk];
  __syncthreads();
  int e0 = blk * CH, e1 = min(E, e0 + CH);
  for (int e = e0 + tid; e < e1; e += 256) {
    int d = dst[e];
    int c = ((u32)d) >> 7;
    u32 p = atomicAdd(&cur[c], 1u);
    u64 it = (u64)(u32)src[e] | ((u64)((u32)d & 127u) << 17) |
             ((u64)__float_as_uint(w[e]) << 24);
    sorted[p] = it;
  }
}

// per-bucket: LDS stage -> 128-bin hist -> ptr/dinv -> in-place node reorder
#define BCAP 6144
__global__ __launch_bounds__(256) void k_bucket(u64* __restrict__ sorted,
                                                const u32* __restrict__ H, int NBLK,
                                                int* __restrict__ ptr, float* __restrict__ dinv,
                                                int N, int E, int NB) {
  __shared__ u64 stage[BCAP];
  __shared__ u32 cnt[128], base[128], cur[128], tmp[128];
  __shared__ float ws[128];
  int c = blockIdx.x, tid = threadIdx.x;
  int b0 = (int)H[(size_t)c * NBLK];
  int b1 = (c + 1 < NB) ? (int)H[(size_t)(c + 1) * NBLK] : E;
  int m = b1 - b0;
  if (tid < 128) { cnt[tid] = 0; ws[tid] = 0.f; }
  __syncthreads();
  for (int i = tid; i < m; i += 256) {
    u64 it = sorted[b0 + i];
    stage[i] = it;
    int lo = (int)((it >> 17) & 127u);
    atomicAdd(&cnt[lo], 1u);
    atomicAdd(&ws[lo], __uint_as_float((u32)(it >> 24)));
  }
  __syncthreads();
  // exclusive scan of cnt[0..127]
  u32 v = (tid < 128) ? cnt[tid] : 0;
  if (tid < 128) tmp[tid] = v;
  __syncthreads();
#pragma unroll
  for (int off = 1; off < 128; off <<= 1) {
    u32 t = 0;
    if (tid < 128 && tid >= off) t = tmp[tid - off];
    __syncthreads();
    if (tid < 128) tmp[tid] += t;
    __syncthreads();
  }
  if (tid < 128) {
    base[tid] = tmp[tid] - v;
    cur[tid] = tmp[tid] - v;
    int node = c * 128 + tid;
    if (node < N) {
      ptr[node] = b0 + (int)base[tid];
      float d = ws[tid];
      dinv[node] = (d > 0.f) ? rsqrtf(fmaxf(d, 1e-30f)) : 0.f;
    }
  }
  if (c == NB - 1 && tid == 0) ptr[N] = E;
  __syncthreads();
  for (int i = tid; i < m; i += 256) {
    u64 it = stage[i];
    int lo = (int)((it >> 17) & 127u);
    u32 p = atomicAdd(&cur[lo], 1u);
    sorted[b0 + (int)p] = it;
  }
}

// norm fixup -> packed ep [norm15|src17]; dst reconstructed from bucket id
__global__ __launch_bounds__(256) void k_pack(const u64* __restrict__ sorted,
                                              const float* __restrict__ dinv,
                                              const u32* __restrict__ H, int NBLK,
                                              u32* __restrict__ ep, int E, int NB) {
  int c = blockIdx.x;
  int b0 = (int)H[(size_t)c * NBLK];
  int b1 = (c + 1 < NB) ? (int)H[(size_t)(c + 1) * NBLK] : E;
  for (int i = b0 + threadIdx.x; i < b1; i += 256) {
    u64 it = sorted[i];
    int s = (int)(it & 0x1FFFFu);
    int dn = c * 128 + (int)((it >> 17) & 127u);
    float wv = __uint_as_float((u32)(it >> 24));
    float nv = dinv[s] * wv * dinv[dn];
    ep[i] = ((u32)f2h(nv) << 17) | (u32)s;
  }
}

// gather t[f4] = sum_e w_e * fp16(hin[src_e][f4]); 2-edge unroll, 4B edges
template <int F4>
__device__ __forceinline__ float4 gather(const int* __restrict__ ptr, const u32* __restrict__ ep,
                                         const ushort4* __restrict__ hin, int node, int f4) {
  int e0 = ptr[node], e1 = ptr[node + 1];
  float4 a = make_float4(0.f, 0.f, 0.f, 0.f);
  int e = e0;
  if ((e & 1) && e < e1) {
    int s0; float w0; dec_ep(ep[e], s0, w0);
    ushort4 h = hin[(size_t)s0 * F4 + f4];
    a.x = fmaf(w0, h2f(h.x), a.x); a.y = fmaf(w0, h2f(h.y), a.y);
    a.z = fmaf(w0, h2f(h.z), a.z); a.w = fmaf(w0, h2f(h.w), a.w);
    ++e;
  }
  for (; e + 1 < e1; e += 2) {
    uint2 p = *(const uint2*)(ep + e);  // 2 edges, 8B aligned
    int s0, s1; float w0, w1;
    dec_ep(p.x, s0, w0);
    dec_ep(p.y, s1, w1);
    ushort4 h0 = hin[(size_t)s0 * F4 + f4];
    ushort4 h1 = hin[(size_t)s1 * F4 + f4];
    a.x = fmaf(w0, h2f(h0.x), a.x); a.y = fmaf(w0, h2f(h0.y), a.y);
    a.z = fmaf(w0, h2f(h0.z), a.z); a.w = fmaf(w0, h2f(h0.w), a.w);
    a.x = fmaf(w1, h2f(h1.x), a.x); a.y = fmaf(w1, h2f(h1.y), a.y);
    a.z = fmaf(w1, h2f(h1.z), a.z); a.w = fmaf(w1, h2f(h1.w), a.w);
  }
  if (e < e1) {
    int s0; float w0; dec_ep(ep[e], s0, w0);
    ushort4 h = hin[(size_t)s0 * F4 + f4];
    a.x = fmaf(w0, h2f(h.x), a.x); a.y = fmaf(w0, h2f(h.y), a.y);
    a.z = fmaf(w0, h2f(h.z), a.z); a.w = fmaf(w0, h2f(h.w), a.w);
  }
  return a;
}

// scalar-broadcast mm accumulate: a += t(slot ln) @ W  (R6's 28-VGPR shape).
// t element i of slot ln lives at word ln*64 + (((i>>2)^ln)<<2 | (i&3)).
// Tile rows are WAVE-PRIVATE (ln = tid>>4): same-wave LDS RAW needs no barrier.
__device__ __forceinline__ void mm_acc(const float* __restrict__ tl, const float4* __restrict__ Wl,
                                       int ln, int j4, float4& a) {
#pragma unroll 8
  for (int i = 0; i < 64; ++i) {
    float tv = tl[ln * 64 + ((((i >> 2) ^ ln) << 2) | (i & 3))];
    float4 wv = Wl[i * 16 + j4];
    a.x = fmaf(tv, wv.x, a.x); a.y = fmaf(tv, wv.y, a.y);
    a.z = fmaf(tv, wv.z, a.z); a.w = fmaf(tv, wv.w, a.w);
  }
}

// ---------- persistent cooperative kernel: layers 2+3 + head ----------
template <int NC>
__global__ __launch_bounds__(256) void mega_k(
    const int* __restrict__ ptr, const u32* __restrict__ ep,
    ushort4* __restrict__ hb0, ushort4* __restrict__ hb1, ushort4* __restrict__ hb2,
    const float* __restrict__ W2, const float* __restrict__ b2,
    const float* __restrict__ Wout, const float* __restrict__ bout,
    float* __restrict__ outv, int n) {
  cg::grid_group grid = cg::this_grid();
  __shared__ float4 Wl[1024];
  __shared__ float4 tl4[256];
  const float* tl = (const float*)tl4;
  const int tid = threadIdx.x, j4 = tid & 15, ln = tid >> 4;
  const int nb = (int)gridDim.x;
  float4 acc[NC];

  for (int L = 0; L < 2; ++L) {
    const float* WL = W2 + (size_t)L * 5 * 4096;
#pragma unroll
    for (int c = 0; c < NC; ++c) acc[c] = make_float4(0.f, 0.f, 0.f, 0.f);

    // ---- own-term pass: acc += h_in @ W0  (h_in = hb2 for both layers) ----
    {
      const float4* W04 = (const float4*)WL;
      for (int i = tid; i < 1024; i += 256) Wl[i] = W04[i];
      __syncthreads();
#pragma unroll
      for (int c = 0; c < NC; ++c) {
        int node = (c * nb + (int)blockIdx.x) * 16 + ln;
        float4 own = make_float4(0.f, 0.f, 0.f, 0.f);
        if (node < n) own = unpack_h(hb2[(size_t)node * 16 + j4]);
        tl4[ln * 16 + (j4 ^ ln)] = own;   // wave-private row, no barrier
        mm_acc(tl, Wl, ln, j4, acc[c]);
      }
      __syncthreads();
    }

    // ---- k = 1..4 propagation phases ----
    for (int k = 1; k <= 4; ++k) {
      const ushort4* gsrc = (k == 1) ? hb2 : ((k == 3) ? hb1 : hb0);
      ushort4* gdst = (k == 2) ? hb1 : hb0;
      const bool last = (k == 4);
      const float4* Wk4 = (const float4*)(WL + (size_t)k * 4096);
      for (int i = tid; i < 1024; i += 256) Wl[i] = Wk4[i];
      __syncthreads();
#pragma unroll
      for (int c = 0; c < NC; ++c) {
        int node = (c * nb + (int)blockIdx.x) * 16 + ln;
        float4 t = make_float4(0.f, 0.f, 0.f, 0.f);
        if (node < n) {
          t = gather<16>(ptr, ep, gsrc, node, j4);
          if (!last) gdst[(size_t)node * 16 + j4] = pack_h(t);
        }
        tl4[ln * 16 + (j4 ^ ln)] = t;     // wave-private, no barrier
        mm_acc(tl, Wl, ln, j4, acc[c]);
      }
      if (last) {  // epilogue: bias + leaky -> layer output (L0) or head (L1)
        const float4* bias4 = (const float4*)(b2 + (size_t)L * 64);
#pragma unroll
        for (int c = 0; c < NC; ++c) {
          int node = (c * nb + (int)blockIdx.x) * 16 + ln;
          if (node >= n) continue;
          float4 a = acc[c];
          float4 b = bias4[j4];
          a.x += b.x; a.y += b.y; a.z += b.z; a.w += b.w;
          a.x = (a.x >= 0.f) ? a.x : 0.01f * a.x;
          a.y = (a.y >= 0.f) ? a.y : 0.01f * a.y;
          a.z = (a.z >= 0.f) ? a.z : 0.01f * a.z;
          a.w = (a.w >= 0.f) ? a.w : 0.01f * a.w;
          if (L == 0) {
            hb2[(size_t)node * 16 + j4] = pack_h(a);
          } else {
            float v = a.x * Wout[4 * j4] + a.y * Wout[4 * j4 + 1] +
                      a.z * Wout[4 * j4 + 2] + a.w * Wout[4 * j4 + 3];
            v += __shfl_down(v, 8, 16);
            v += __shfl_down(v, 4, 16);
            v += __shfl_down(v, 2, 16);
            v += __shfl_down(v, 1, 16);
            if (j4 == 0) outv[node] = v + bout[0];
          }
        }
      }
      if (!(L == 1 && k == 4)) {
        __threadfence();  // device-scope release of gdst/hb2 stores
        grid.sync();      // phase boundary (covers block sync for Wl reload)
      }
    }
  }
}

// ---------- fallback fused prop + matmul, F=64 (R10, fp16 acc) ----------
template <bool FIRST, bool LAST, bool HEAD>
__launch_bounds__(256)
__global__ void ptag64_k(const int* __restrict__ ptr, const u32* __restrict__ ep,
                         const ushort4* __restrict__ hin, ushort4* __restrict__ hout,
                         const float4* __restrict__ Wk4, const float4* __restrict__ W04,
                         ushort4* __restrict__ acch, const float4* __restrict__ bias4,
                         const float* __restrict__ Wout, const float* __restrict__ bout,
                         float* __restrict__ outv, int n) {
  __shared__ float4 Wl[1024];
  __shared__ float4 tl4[256];
  const float* tl = (const float*)tl4;
  int tid = threadIdx.x;
  for (int i = tid; i < 1024; i += 256) Wl[i] = Wk4[i];
  int gid = blockIdx.x * 256 + tid;
  int node = gid >> 4, j4 = gid & 15, ln = tid >> 4;

  float4 t = make_float4(0.f, 0.f, 0.f, 0.f);
  if (node < n) {
    t = gather<16>(ptr, ep, hin, node, j4);
    if (!LAST) hout[(size_t)node * 16 + j4] = pack_h(t);
  }
  tl4[ln * 16 + (j4 ^ ln)] = t;
  __syncthreads();

  float4 a = make_float4(0.f, 0.f, 0.f, 0.f);
  if (!FIRST && node < n) a = unpack_h(acch[(size_t)node * 16 + j4]);
  mm_acc(tl, Wl, ln, j4, a);
  if (FIRST) {
    __syncthreads();
    for (int i = tid; i < 1024; i += 256) Wl[i] = W04[i];
    float4 own = make_float4(0.f, 0.f, 0.f, 0.f);
    if (node < n) own = unpack_h(hin[(size_t)node * 16 + j4]);
    tl4[ln * 16 + (j4 ^ ln)] = own;
    __syncthreads();
    mm_acc(tl, Wl, ln, j4, a);
  }
  if (node >= n) return;

  if (LAST) {
    float4 b = bias4[j4];
    a.x += b.x; a.y += b.y; a.z += b.z; a.w += b.w;
    a.x = (a.x >= 0.f) ? a.x : 0.01f * a.x;
    a.y = (a.y >= 0.f) ? a.y : 0.01f * a.y;
    a.z = (a.z >= 0.f) ? a.z : 0.01f * a.z;
    a.w = (a.w >= 0.f) ? a.w : 0.01f * a.w;
    if (HEAD) {
      float v = a.x * Wout[4 * j4] + a.y * Wout[4 * j4 + 1] +
                a.z * Wout[4 * j4 + 2] + a.w * Wout[4 * j4 + 3];
      v += __shfl_down(v, 8, 16);
      v += __shfl_down(v, 4, 16);
      v += __shfl_down(v, 2, 16);
      v += __shfl_down(v, 1, 16);
      if (j4 == 0) outv[node] = v + bout[0];
    } else {
      hout[(size_t)node * 16 + j4] = pack_h(a);
    }
  } else {
    acch[(size_t)node * 16 + j4] = pack_h(a);
  }
}

// ---------- fused prop + matmul, layer 1: F_in=16 (4 lanes/node) ----------
template <bool FIRST, bool LAST>
__launch_bounds__(256)
__global__ void ptag16_k(const int* __restrict__ ptr, const u32* __restrict__ ep,
                         const ushort4* __restrict__ hin, ushort4* __restrict__ hout,
                         const float4* __restrict__ Wk4, const float4* __restrict__ W04,
                         ushort4* __restrict__ acch, const float4* __restrict__ bias4,
                         ushort4* __restrict__ outbuf, int n) {
  __shared__ float4 Wl[256];
  __shared__ float4 W0l[FIRST ? 256 : 1];
  __shared__ float4 tl4[64 * 5];
  const float* tl = (const float*)tl4;
  int tid = threadIdx.x;
  Wl[tid] = Wk4[tid];
  if (FIRST) W0l[tid] = W04[tid];
  int gid = blockIdx.x * 256 + tid;
  int node = gid >> 2, q = tid & 3, ln = tid >> 2;

  float4 t = make_float4(0.f, 0.f, 0.f, 0.f);
  if (node < n) {
    t = gather<4>(ptr, ep, hin, node, q);
    if (!LAST) hout[(size_t)node * 4 + q] = pack_h(t);
  }
  tl4[ln * 5 + q] = t;
  __syncthreads();

  float4 a[4];
#pragma unroll
  for (int c = 0; c < 4; ++c) a[c] = make_float4(0.f, 0.f, 0.f, 0.f);
  if (!FIRST && node < n) {
#pragma unroll
    for (int c = 0; c < 4; ++c) a[c] = unpack_h(acch[(size_t)node * 16 + 4 * q + c]);
  }
#pragma unroll 4
  for (int i = 0; i < 16; ++i) {
    float tv = tl[ln * 20 + i];
#pragma unroll
    for (int c = 0; c < 4; ++c) {
      float4 wv = Wl[i * 16 + 4 * q + c];
      a[c].x = fmaf(tv, wv.x, a[c].x); a[c].y = fmaf(tv, wv.y, a[c].y);
      a[c].z = fmaf(tv, wv.z, a[c].z); a[c].w = fmaf(tv, wv.w, a[c].w);
    }
  }
  if (FIRST) {
    __syncthreads();
    float4 own = make_float4(0.f, 0.f, 0.f, 0.f);
    if (node < n) own = unpack_h(hin[(size_t)node * 4 + q]);
    tl4[ln * 5 + q] = own;
    __syncthreads();
#pragma unroll 4
    for (int i = 0; i < 16; ++i) {
      float tv = tl[ln * 20 + i];
#pragma unroll
      for (int c = 0; c < 4; ++c) {
        float4 wv = W0l[i * 16 + 4 * q + c];
        a[c].x = fmaf(tv, wv.x, a[c].x); a[c].y = fmaf(tv, wv.y, a[c].y);
        a[c].z = fmaf(tv, wv.z, a[c].z); a[c].w = fmaf(tv, wv.w, a[c].w);
      }
    }
  }
  if (node >= n) return;

  if (LAST) {
#pragma unroll
    for (int c = 0; c < 4; ++c) {
      float4 b = bias4[4 * q + c];
      a[c].x += b.x; a[c].y += b.y; a[c].z += b.z; a[c].w += b.w;
      a[c].x = (a[c].x >= 0.f) ? a[c].x : 0.01f * a[c].x;
      a[c].y = (a[c].y >= 0.f) ? a[c].y : 0.01f * a[c].y;
      a[c].z = (a[c].z >= 0.f) ? a[c].z : 0.01f * a[c].z;
      a[c].w = (a[c].w >= 0.f) ? a[c].w : 0.01f * a[c].w;
      outbuf[(size_t)node * 16 + 4 * q + c] = pack_h(a[c]);
    }
  } else {
#pragma unroll
    for (int c = 0; c < 4; ++c) acch[(size_t)node * 16 + 4 * q + c] = pack_h(a[c]);
  }
}

extern "C" void kernel_launch(void* const* d_in, const int* in_sizes, int n_in,
                              void* d_out, int out_size, void* d_ws, size_t ws_size,
                              hipStream_t stream) {
  const float* x    = (const float*)d_in[0];
  const int*   ei   = (const int*)d_in[1];
  const float* ew   = (const float*)d_in[2];
  const float* W1   = (const float*)d_in[4];
  const float* b1   = (const float*)d_in[5];
  const float* W2   = (const float*)d_in[6];
  const float* b2   = (const float*)d_in[7];
  const float* Wout = (const float*)d_in[8];
  const float* bout = (const float*)d_in[9];
  float* out = (float*)d_out;

  const int N = in_sizes[0] / 16;
  const int E = in_sizes[2];
  const int* src = ei;
  const int* dst = ei + E;

  const int NBLK = 256;                      // persistent blocks for hist/scatter
  const int CH = (E + NBLK - 1) / NBLK;      // edges per block
  const int NB = (N + 127) >> 7;             // coarse buckets (<=1024 for N<=131072)
  const int HN = NB * NBLK;                  // hist entries (multiple of 256)

  char* ws = (char*)d_ws;
  size_t off = 0;
  auto alloc = [&](size_t bytes) {
    char* p = ws + off;
    off = (off + bytes + 255) & ~(size_t)255;
    return p;
  };
  u32*     H      = (u32*)alloc((size_t)HN * 4);             // (bucket,block) hist/bases
  u32*     bsum   = (u32*)alloc(4096);
  float*   dinv   = (float*)alloc((size_t)N * 4);
  int*     ptr    = (int*)alloc(((size_t)N + 1) * 4);
  u64*     sorted = (u64*)alloc((size_t)E * 8);              // [w_f32|dstlow7|src17]
  u32*     ep     = (u32*)alloc((size_t)E * 4);              // packed 4B edges
  ushort4* xh     = (ushort4*)alloc((size_t)N * 16 * 2);     // N x 16 fp16
  ushort4* hb0    = (ushort4*)alloc((size_t)N * 64 * 2);     // t ping
  ushort4* hb1    = (ushort4*)alloc((size_t)N * 64 * 2);     // t pong
  ushort4* hb2    = (ushort4*)alloc((size_t)N * 64 * 2);     // layer outputs
  ushort4* acch   = (ushort4*)alloc((size_t)N * 64 * 2);     // fp16 acc (layer1/fallback)

  // ---- atomic-free CSR build ----
  k_hist<<<NBLK, 256, 0, stream>>>(dst, H, E, CH, NB, (const float4*)x, xh, N * 4);
  scanH_blocks<<<HN / 256, 256, 0, stream>>>(H, bsum, HN);
  scanH_sums<<<1, 1024, 0, stream>>>(bsum, HN / 256);
  scanH_add<<<HN / 256, 256, 0, stream>>>(H, bsum, HN);
  k_scatter<<<NBLK, 256, 0, stream>>>(src, dst, ew, H, sorted, E, CH, NB);
  k_bucket<<<NB, 256, 0, stream>>>(sorted, H, NBLK, ptr, dinv, N, E, NB);
  k_pack<<<NB, 256, 0, stream>>>(sorted, dinv, H, NBLK, ep, E, NB);

  int g4  = (N * 4 + 255) / 256;   // layer-1 fused (4 lanes/node)
  int g16 = (N * 16 + 255) / 256;  // fallback F=64 fused

  auto W1k = [&](int k) { return (const float4*)(W1 + (size_t)k * 1024); };
  auto W2k = [&](int l, int k) { return (const float4*)(W2 + ((size_t)l * 5 + k) * 4096); };

  // ---- Layer 1 (16 -> 64): acc in acch, t ping-pong hb0/hb1, h1 -> hb2 ----
  ptag16_k<true,  false><<<g4, 256, 0, stream>>>(ptr, ep, xh,  hb0, W1k(1), W1k(0), acch, nullptr, nullptr, N);
  ptag16_k<false, false><<<g4, 256, 0, stream>>>(ptr, ep, hb0, hb1, W1k(2), nullptr, acch, nullptr, nullptr, N);
  ptag16_k<false, false><<<g4, 256, 0, stream>>>(ptr, ep, hb1, hb0, W1k(3), nullptr, acch, nullptr, nullptr, N);
  ptag16_k<false, true ><<<g4, 256, 0, stream>>>(ptr, ep, hb0, nullptr, W1k(4), nullptr, acch,
                                                 (const float4*)b1, hb2, N);

  // ---- Layers 2+3 + head: persistent cooperative kernel (occupancy-gated) ----
  int maxB4 = 0, maxB5 = 0, maxB7 = 0;
  (void)hipOccupancyMaxActiveBlocksPerMultiprocessor(&maxB4, mega_k<4>, 256, 0);
  (void)hipOccupancyMaxActiveBlocksPerMultiprocessor(&maxB5, mega_k<5>, 256, 0);
  (void)hipOccupancyMaxActiveBlocksPerMultiprocessor(&maxB7, mega_k<7>, 256, 0);
  void* fn = nullptr;
  int grid = 0;
  if ((long)maxB4 * 256 * 16 * 4 >= (long)N) {
    fn = (void*)mega_k<4>; grid = maxB4 * 256;
  } else if ((long)maxB5 * 256 * 16 * 5 >= (long)N) {
    fn = (void*)mega_k<5>; grid = maxB5 * 256;
  } else if ((long)maxB7 * 256 * 16 * 7 >= (long)N) {
    fn = (void*)mega_k<7>; grid = maxB7 * 256;
  }

  if (fn) {
    const int* ptrA = ptr; const u32* epA = ep;
    ushort4 *h0A = hb0, *h1A = hb1, *h2A = hb2;
    const float *W2A = W2, *b2A = b2, *WoA = Wout, *boA = bout;
    float* outA = out; int nA = N;
    void* args[] = {&ptrA, &epA, &h0A, &h1A, &h2A, &W2A, &b2A, &WoA, &boA, &outA, &nA};
    hipLaunchCooperativeKernel(fn, dim3(grid), dim3(256), args, 0, stream);
  } else {
    // fallback: R10's proven dispatch sequence
    ptag64_k<true,  false, false><<<g16, 256, 0, stream>>>(ptr, ep, hb2, hb0, W2k(0,1), W2k(0,0), acch,
                                                           nullptr, nullptr, nullptr, nullptr, N);
    ptag64_k<false, false, false><<<g16, 256, 0, stream>>>(ptr, ep, hb0, hb1, W2k(0,2), nullptr, acch,
                                                           nullptr, nullptr, nullptr, nullptr, N);
    ptag64_k<false, false, false><<<g16, 256, 0, stream>>>(ptr, ep, hb1, hb0, W2k(0,3), nullptr, acch,
                                                           nullptr, nullptr, nullptr, nullptr, N);
    ptag64_k<false, true,  false><<<g16, 256, 0, stream>>>(ptr, ep, hb0, hb2, W2k(0,4), nullptr, acch,
                                                           (const float4*)b2, nullptr, nullptr, nullptr, N);
    ptag64_k<true,  false, false><<<g16, 256, 0, stream>>>(ptr, ep, hb2, hb0, W2k(1,1), W2k(1,0), acch,
                                                           nullptr, nullptr, nullptr, nullptr, N);
    ptag64_k<false, false, false><<<g16, 256, 0, stream>>>(ptr, ep, hb0, hb1, W2k(1,2), nullptr, acch,
                                                           nullptr, nullptr, nullptr, nullptr, N);
    ptag64_k<false, false, false><<<g16, 256, 0, stream>>>(ptr, ep, hb1, hb0, W2k(1,3), nullptr, acch,
                                                           nullptr, nullptr, nullptr, nullptr, N);
    ptag64_k<false, true,  true ><<<g16, 256, 0, stream>>>(ptr, ep, hb0, nullptr, W2k(1,4), nullptr, acch,
                                                           (const float4*)(b2 + 64), Wout, bout, out, N);
  }
}

// Round 3
// 1000.900 us; speedup vs baseline: 1.1856x; 1.0886x over previous
//
#include <hip/hip_runtime.h>
#include <hip/hip_cooperative_groups.h>

namespace cg = cooperative_groups;

// ---------------------------------------------------------------------------
// TAGCN node regression: 3 TAGConv layers (K=4) + linear head, fp32 math.
// R14: zero-global-atomic CSR build (two-level bucket sort) - degcount's
// 155us/115MB atomic tax eliminated.
// R15: gather() was latency-bound (ptag64 102us @ 23% HBM, 58% VALU, MLP=2,
// hin loads dependent on same-iter ep load). Rewrite as 4-edge quads
// (uint4 ep load) with 1-deep software pipeline: next quad's ep + 4 hin
// loads issued before current quad's FMAs. MLP ~5/thread.
// KNOWN (R15 discovery): mega_k coop path has NEVER run - occupancy query
// accounts LDS vs 64KiB -> maxB=3 -> all NC gates fail -> ptag64 fallback
// is the real execution path. Gate fix deferred for attribution.
// ---------------------------------------------------------------------------

typedef unsigned long long u64;
typedef unsigned int u32;

__device__ __forceinline__ float h2f(unsigned short u) {
  _Float16 h;
  __builtin_memcpy(&h, &u, 2);
  return (float)h;
}
__device__ __forceinline__ unsigned short f2h(float f) {
  _Float16 h = (_Float16)f;  // RNE
  unsigned short u;
  __builtin_memcpy(&u, &h, 2);
  return u;
}
__device__ __forceinline__ ushort4 pack_h(float4 v) {
  ushort4 r;
  r.x = f2h(v.x); r.y = f2h(v.y); r.z = f2h(v.z); r.w = f2h(v.w);
  return r;
}
__device__ __forceinline__ float4 unpack_h(ushort4 u) {
  return make_float4(h2f(u.x), h2f(u.y), h2f(u.z), h2f(u.w));
}
// packed edge: [norm15 | src17]
__device__ __forceinline__ void dec_ep(u32 u, int& s, float& w) {
  s = (int)(u & 0x1FFFFu);
  w = h2f((unsigned short)(u >> 17));
}

// ---------------- atomic-free CSR build ----------------
// coarse bucket = dst >> 7 (128 nodes/bucket). NB <= 1024 (N <= 131072).
// item u64 = [0:8][w_f32:32][dst_low7:7][src:17]

// per-block LDS hist of dst>>7 -> H[bucket*NBLK + blk]; fused x->fp16
__global__ __launch_bounds__(256) void k_hist(const int* __restrict__ dst, u32* __restrict__ H,
                                              int E, int CH, int NB,
                                              const float4* __restrict__ x4,
                                              ushort4* __restrict__ xh, int n4) {
  __shared__ u32 hc[1024];
  int tid = threadIdx.x, blk = blockIdx.x, nblk = gridDim.x;
  for (int i = tid; i < 1024; i += 256) hc[i] = 0;
  for (int i = blk * 256 + tid; i < n4; i += nblk * 256) xh[i] = pack_h(x4[i]);
  __syncthreads();
  int e0 = blk * CH, e1 = min(E, e0 + CH);
  for (int e = e0 + tid; e < e1; e += 256) atomicAdd(&hc[((u32)dst[e]) >> 7], 1u);
  __syncthreads();
  for (int c = tid; c < NB; c += 256) H[(size_t)c * nblk + blk] = hc[c];
}

// exclusive scan of H (n = NB*256 entries), 256/block
__global__ void scanH_blocks(u32* __restrict__ H, u32* __restrict__ bsum, int n) {
  __shared__ u32 s[256];
  int tid = threadIdx.x;
  int i = blockIdx.x * 256 + tid;
  u32 v = (i < n) ? H[i] : 0;
  s[tid] = v;
  __syncthreads();
#pragma unroll
  for (int off = 1; off < 256; off <<= 1) {
    u32 t = (tid >= off) ? s[tid - off] : 0;
    __syncthreads();
    s[tid] += t;
    __syncthreads();
  }
  if (i < n) H[i] = s[tid] - v;
  if (tid == 255) bsum[blockIdx.x] = s[255];
}

__global__ void scanH_sums(u32* __restrict__ bsum, int nb) {
  __shared__ u32 s[1024];
  int tid = threadIdx.x;
  u32 v = (tid < nb) ? bsum[tid] : 0;
  s[tid] = v;
  __syncthreads();
#pragma unroll
  for (int off = 1; off < 1024; off <<= 1) {
    u32 t = (tid >= off) ? s[tid - off] : 0;
    __syncthreads();
    s[tid] += t;
    __syncthreads();
  }
  if (tid < nb) bsum[tid] = s[tid] - v;
}

__global__ void scanH_add(u32* __restrict__ H, const u32* __restrict__ bsum, int n) {
  int i = blockIdx.x * blockDim.x + threadIdx.x;
  if (i < n) H[i] += bsum[i >> 8];
}

// scatter edges into coarse-bucket regions via LDS cursors (no global atomics)
__global__ __launch_bounds__(256) void k_scatter(const int* __restrict__ src,
                                                 const int* __restrict__ dst,
                                                 const float* __restrict__ w,
                                                 const u32* __restrict__ H,
                                                 u64* __restrict__ sorted, int E, int CH, int NB) {
  __shared__ u32 cur[1024];
  int tid = threadIdx.x, blk = blockIdx.x, nblk = gridDim.x;
  for (int c = tid; c < NB; c += 256) cur[c] = H[(size_t)c * nblk + blk];
  __syncthreads();
  int e0 = blk * CH, e1 = min(E, e0 + CH);
  for (int e = e0 + tid; e < e1; e += 256) {
    int d = dst[e];
    int c = ((u32)d) >> 7;
    u32 p = atomicAdd(&cur[c], 1u);
    u64 it = (u64)(u32)src[e] | ((u64)((u32)d & 127u) << 17) |
             ((u64)__float_as_uint(w[e]) << 24);
    sorted[p] = it;
  }
}

// per-bucket: LDS stage -> 128-bin hist -> ptr/dinv -> in-place node reorder
#define BCAP 6144
__global__ __launch_bounds__(256) void k_bucket(u64* __restrict__ sorted,
                                                const u32* __restrict__ H, int NBLK,
                                                int* __restrict__ ptr, float* __restrict__ dinv,
                                                int N, int E, int NB) {
  __shared__ u64 stage[BCAP];
  __shared__ u32 cnt[128], base[128], cur[128], tmp[128];
  __shared__ float ws[128];
  int c = blockIdx.x, tid = threadIdx.x;
  int b0 = (int)H[(size_t)c * NBLK];
  int b1 = (c + 1 < NB) ? (int)H[(size_t)(c + 1) * NBLK] : E;
  int m = b1 - b0;
  if (tid < 128) { cnt[tid] = 0; ws[tid] = 0.f; }
  __syncthreads();
  for (int i = tid; i < m; i += 256) {
    u64 it = sorted[b0 + i];
    stage[i] = it;
    int lo = (int)((it >> 17) & 127u);
    atomicAdd(&cnt[lo], 1u);
    atomicAdd(&ws[lo], __uint_as_float((u32)(it >> 24)));
  }
  __syncthreads();
  // exclusive scan of cnt[0..127]
  u32 v = (tid < 128) ? cnt[tid] : 0;
  if (tid < 128) tmp[tid] = v;
  __syncthreads();
#pragma unroll
  for (int off = 1; off < 128; off <<= 1) {
    u32 t = 0;
    if (tid < 128 && tid >= off) t = tmp[tid - off];
    __syncthreads();
    if (tid < 128) tmp[tid] += t;
    __syncthreads();
  }
  if (tid < 128) {
    base[tid] = tmp[tid] - v;
    cur[tid] = tmp[tid] - v;
    int node = c * 128 + tid;
    if (node < N) {
      ptr[node] = b0 + (int)base[tid];
      float d = ws[tid];
      dinv[node] = (d > 0.f) ? rsqrtf(fmaxf(d, 1e-30f)) : 0.f;
    }
  }
  if (c == NB - 1 && tid == 0) ptr[N] = E;
  __syncthreads();
  for (int i = tid; i < m; i += 256) {
    u64 it = stage[i];
    int lo = (int)((it >> 17) & 127u);
    u32 p = atomicAdd(&cur[lo], 1u);
    sorted[b0 + (int)p] = it;
  }
}

// norm fixup -> packed ep [norm15|src17]; dst reconstructed from bucket id
__global__ __launch_bounds__(256) void k_pack(const u64* __restrict__ sorted,
                                              const float* __restrict__ dinv,
                                              const u32* __restrict__ H, int NBLK,
                                              u32* __restrict__ ep, int E, int NB) {
  int c = blockIdx.x;
  int b0 = (int)H[(size_t)c * NBLK];
  int b1 = (c + 1 < NB) ? (int)H[(size_t)(c + 1) * NBLK] : E;
  for (int i = b0 + threadIdx.x; i < b1; i += 256) {
    u64 it = sorted[i];
    int s = (int)(it & 0x1FFFFu);
    int dn = c * 128 + (int)((it >> 17) & 127u);
    float wv = __uint_as_float((u32)(it >> 24));
    float nv = dinv[s] * wv * dinv[dn];
    ep[i] = ((u32)f2h(nv) << 17) | (u32)s;
  }
}

// ---- R15 gather: 4-edge quads, 1-deep software pipeline ----
__device__ __forceinline__ void acc_e(float4& a, u32 pe, ushort4 h) {
  float w = h2f((unsigned short)(pe >> 17));
  a.x = fmaf(w, h2f(h.x), a.x); a.y = fmaf(w, h2f(h.y), a.y);
  a.z = fmaf(w, h2f(h.z), a.z); a.w = fmaf(w, h2f(h.w), a.w);
}

template <int F4>
__device__ __forceinline__ float4 gather(const int* __restrict__ ptr, const u32* __restrict__ ep,
                                         const ushort4* __restrict__ hin, int node, int f4) {
  int e0 = ptr[node], e1 = ptr[node + 1];
  float4 a = make_float4(0.f, 0.f, 0.f, 0.f);
  int e = e0;
  // head: align to 4-edge (16B) boundary
  while (e < e1 && (e & 3)) {
    u32 pe = ep[e];
    acc_e(a, pe, hin[(size_t)(pe & 0x1FFFFu) * F4 + f4]);
    ++e;
  }
  int nq = (e1 - e) >> 2;
  if (nq > 0) {
    uint4 p = *(const uint4*)(ep + e);
    ushort4 h0 = hin[(size_t)(p.x & 0x1FFFFu) * F4 + f4];
    ushort4 h1 = hin[(size_t)(p.y & 0x1FFFFu) * F4 + f4];
    ushort4 h2 = hin[(size_t)(p.z & 0x1FFFFu) * F4 + f4];
    ushort4 h3 = hin[(size_t)(p.w & 0x1FFFFu) * F4 + f4];
    for (int q = 1; q < nq; ++q) {
      uint4 pn = *(const uint4*)(ep + e + 4 * q);   // next quad's edges
      ushort4 g0 = hin[(size_t)(pn.x & 0x1FFFFu) * F4 + f4];
      ushort4 g1 = hin[(size_t)(pn.y & 0x1FFFFu) * F4 + f4];
      ushort4 g2 = hin[(size_t)(pn.z & 0x1FFFFu) * F4 + f4];
      ushort4 g3 = hin[(size_t)(pn.w & 0x1FFFFu) * F4 + f4];
      acc_e(a, p.x, h0); acc_e(a, p.y, h1);         // FMAs on current quad
      acc_e(a, p.z, h2); acc_e(a, p.w, h3);         // (loads above in flight)
      p = pn; h0 = g0; h1 = g1; h2 = g2; h3 = g3;
    }
    acc_e(a, p.x, h0); acc_e(a, p.y, h1);
    acc_e(a, p.z, h2); acc_e(a, p.w, h3);
    e += nq * 4;
  }
  // tail
  while (e < e1) {
    u32 pe = ep[e];
    acc_e(a, pe, hin[(size_t)(pe & 0x1FFFFu) * F4 + f4]);
    ++e;
  }
  return a;
}

// scalar-broadcast mm accumulate: a += t(slot ln) @ W  (R6's 28-VGPR shape).
// t element i of slot ln lives at word ln*64 + (((i>>2)^ln)<<2 | (i&3)).
// Tile rows are WAVE-PRIVATE (ln = tid>>4): same-wave LDS RAW needs no barrier.
__device__ __forceinline__ void mm_acc(const float* __restrict__ tl, const float4* __restrict__ Wl,
                                       int ln, int j4, float4& a) {
#pragma unroll 8
  for (int i = 0; i < 64; ++i) {
    float tv = tl[ln * 64 + ((((i >> 2) ^ ln) << 2) | (i & 3))];
    float4 wv = Wl[i * 16 + j4];
    a.x = fmaf(tv, wv.x, a.x); a.y = fmaf(tv, wv.y, a.y);
    a.z = fmaf(tv, wv.z, a.z); a.w = fmaf(tv, wv.w, a.w);
  }
}

// ---------- persistent cooperative kernel: layers 2+3 + head ----------
template <int NC>
__global__ __launch_bounds__(256) void mega_k(
    const int* __restrict__ ptr, const u32* __restrict__ ep,
    ushort4* __restrict__ hb0, ushort4* __restrict__ hb1, ushort4* __restrict__ hb2,
    const float* __restrict__ W2, const float* __restrict__ b2,
    const float* __restrict__ Wout, const float* __restrict__ bout,
    float* __restrict__ outv, int n) {
  cg::grid_group grid = cg::this_grid();
  __shared__ float4 Wl[1024];
  __shared__ float4 tl4[256];
  const float* tl = (const float*)tl4;
  const int tid = threadIdx.x, j4 = tid & 15, ln = tid >> 4;
  const int nb = (int)gridDim.x;
  float4 acc[NC];

  for (int L = 0; L < 2; ++L) {
    const float* WL = W2 + (size_t)L * 5 * 4096;
#pragma unroll
    for (int c = 0; c < NC; ++c) acc[c] = make_float4(0.f, 0.f, 0.f, 0.f);

    // ---- own-term pass: acc += h_in @ W0  (h_in = hb2 for both layers) ----
    {
      const float4* W04 = (const float4*)WL;
      for (int i = tid; i < 1024; i += 256) Wl[i] = W04[i];
      __syncthreads();
#pragma unroll
      for (int c = 0; c < NC; ++c) {
        int node = (c * nb + (int)blockIdx.x) * 16 + ln;
        float4 own = make_float4(0.f, 0.f, 0.f, 0.f);
        if (node < n) own = unpack_h(hb2[(size_t)node * 16 + j4]);
        tl4[ln * 16 + (j4 ^ ln)] = own;   // wave-private row, no barrier
        mm_acc(tl, Wl, ln, j4, acc[c]);
      }
      __syncthreads();
    }

    // ---- k = 1..4 propagation phases ----
    for (int k = 1; k <= 4; ++k) {
      const ushort4* gsrc = (k == 1) ? hb2 : ((k == 3) ? hb1 : hb0);
      ushort4* gdst = (k == 2) ? hb1 : hb0;
      const bool last = (k == 4);
      const float4* Wk4 = (const float4*)(WL + (size_t)k * 4096);
      for (int i = tid; i < 1024; i += 256) Wl[i] = Wk4[i];
      __syncthreads();
#pragma unroll
      for (int c = 0; c < NC; ++c) {
        int node = (c * nb + (int)blockIdx.x) * 16 + ln;
        float4 t = make_float4(0.f, 0.f, 0.f, 0.f);
        if (node < n) {
          t = gather<16>(ptr, ep, gsrc, node, j4);
          if (!last) gdst[(size_t)node * 16 + j4] = pack_h(t);
        }
        tl4[ln * 16 + (j4 ^ ln)] = t;     // wave-private, no barrier
        mm_acc(tl, Wl, ln, j4, acc[c]);
      }
      if (last) {  // epilogue: bias + leaky -> layer output (L0) or head (L1)
        const float4* bias4 = (const float4*)(b2 + (size_t)L * 64);
#pragma unroll
        for (int c = 0; c < NC; ++c) {
          int node = (c * nb + (int)blockIdx.x) * 16 + ln;
          if (node >= n) continue;
          float4 a = acc[c];
          float4 b = bias4[j4];
          a.x += b.x; a.y += b.y; a.z += b.z; a.w += b.w;
          a.x = (a.x >= 0.f) ? a.x : 0.01f * a.x;
          a.y = (a.y >= 0.f) ? a.y : 0.01f * a.y;
          a.z = (a.z >= 0.f) ? a.z : 0.01f * a.z;
          a.w = (a.w >= 0.f) ? a.w : 0.01f * a.w;
          if (L == 0) {
            hb2[(size_t)node * 16 + j4] = pack_h(a);
          } else {
            float v = a.x * Wout[4 * j4] + a.y * Wout[4 * j4 + 1] +
                      a.z * Wout[4 * j4 + 2] + a.w * Wout[4 * j4 + 3];
            v += __shfl_down(v, 8, 16);
            v += __shfl_down(v, 4, 16);
            v += __shfl_down(v, 2, 16);
            v += __shfl_down(v, 1, 16);
            if (j4 == 0) outv[node] = v + bout[0];
          }
        }
      }
      if (!(L == 1 && k == 4)) {
        __threadfence();  // device-scope release of gdst/hb2 stores
        grid.sync();      // phase boundary (covers block sync for Wl reload)
      }
    }
  }
}

// ---------- fallback fused prop + matmul, F=64 (R10, fp16 acc) ----------
template <bool FIRST, bool LAST, bool HEAD>
__launch_bounds__(256)
__global__ void ptag64_k(const int* __restrict__ ptr, const u32* __restrict__ ep,
                         const ushort4* __restrict__ hin, ushort4* __restrict__ hout,
                         const float4* __restrict__ Wk4, const float4* __restrict__ W04,
                         ushort4* __restrict__ acch, const float4* __restrict__ bias4,
                         const float* __restrict__ Wout, const float* __restrict__ bout,
                         float* __restrict__ outv, int n) {
  __shared__ float4 Wl[1024];
  __shared__ float4 tl4[256];
  const float* tl = (const float*)tl4;
  int tid = threadIdx.x;
  for (int i = tid; i < 1024; i += 256) Wl[i] = Wk4[i];
  int gid = blockIdx.x * 256 + tid;
  int node = gid >> 4, j4 = gid & 15, ln = tid >> 4;

  float4 t = make_float4(0.f, 0.f, 0.f, 0.f);
  if (node < n) {
    t = gather<16>(ptr, ep, hin, node, j4);
    if (!LAST) hout[(size_t)node * 16 + j4] = pack_h(t);
  }
  tl4[ln * 16 + (j4 ^ ln)] = t;
  __syncthreads();

  float4 a = make_float4(0.f, 0.f, 0.f, 0.f);
  if (!FIRST && node < n) a = unpack_h(acch[(size_t)node * 16 + j4]);
  mm_acc(tl, Wl, ln, j4, a);
  if (FIRST) {
    __syncthreads();
    for (int i = tid; i < 1024; i += 256) Wl[i] = W04[i];
    float4 own = make_float4(0.f, 0.f, 0.f, 0.f);
    if (node < n) own = unpack_h(hin[(size_t)node * 16 + j4]);
    tl4[ln * 16 + (j4 ^ ln)] = own;
    __syncthreads();
    mm_acc(tl, Wl, ln, j4, a);
  }
  if (node >= n) return;

  if (LAST) {
    float4 b = bias4[j4];
    a.x += b.x; a.y += b.y; a.z += b.z; a.w += b.w;
    a.x = (a.x >= 0.f) ? a.x : 0.01f * a.x;
    a.y = (a.y >= 0.f) ? a.y : 0.01f * a.y;
    a.z = (a.z >= 0.f) ? a.z : 0.01f * a.z;
    a.w = (a.w >= 0.f) ? a.w : 0.01f * a.w;
    if (HEAD) {
      float v = a.x * Wout[4 * j4] + a.y * Wout[4 * j4 + 1] +
                a.z * Wout[4 * j4 + 2] + a.w * Wout[4 * j4 + 3];
      v += __shfl_down(v, 8, 16);
      v += __shfl_down(v, 4, 16);
      v += __shfl_down(v, 2, 16);
      v += __shfl_down(v, 1, 16);
      if (j4 == 0) outv[node] = v + bout[0];
    } else {
      hout[(size_t)node * 16 + j4] = pack_h(a);
    }
  } else {
    acch[(size_t)node * 16 + j4] = pack_h(a);
  }
}

// ---------- fused prop + matmul, layer 1: F_in=16 (4 lanes/node) ----------
template <bool FIRST, bool LAST>
__launch_bounds__(256)
__global__ void ptag16_k(const int* __restrict__ ptr, const u32* __restrict__ ep,
                         const ushort4* __restrict__ hin, ushort4* __restrict__ hout,
                         const float4* __restrict__ Wk4, const float4* __restrict__ W04,
                         ushort4* __restrict__ acch, const float4* __restrict__ bias4,
                         ushort4* __restrict__ outbuf, int n) {
  __shared__ float4 Wl[256];
  __shared__ float4 W0l[FIRST ? 256 : 1];
  __shared__ float4 tl4[64 * 5];
  const float* tl = (const float*)tl4;
  int tid = threadIdx.x;
  Wl[tid] = Wk4[tid];
  if (FIRST) W0l[tid] = W04[tid];
  int gid = blockIdx.x * 256 + tid;
  int node = gid >> 2, q = tid & 3, ln = tid >> 2;

  float4 t = make_float4(0.f, 0.f, 0.f, 0.f);
  if (node < n) {
    t = gather<4>(ptr, ep, hin, node, q);
    if (!LAST) hout[(size_t)node * 4 + q] = pack_h(t);
  }
  tl4[ln * 5 + q] = t;
  __syncthreads();

  float4 a[4];
#pragma unroll
  for (int c = 0; c < 4; ++c) a[c] = make_float4(0.f, 0.f, 0.f, 0.f);
  if (!FIRST && node < n) {
#pragma unroll
    for (int c = 0; c < 4; ++c) a[c] = unpack_h(acch[(size_t)node * 16 + 4 * q + c]);
  }
#pragma unroll 4
  for (int i = 0; i < 16; ++i) {
    float tv = tl[ln * 20 + i];
#pragma unroll
    for (int c = 0; c < 4; ++c) {
      float4 wv = Wl[i * 16 + 4 * q + c];
      a[c].x = fmaf(tv, wv.x, a[c].x); a[c].y = fmaf(tv, wv.y, a[c].y);
      a[c].z = fmaf(tv, wv.z, a[c].z); a[c].w = fmaf(tv, wv.w, a[c].w);
    }
  }
  if (FIRST) {
    __syncthreads();
    float4 own = make_float4(0.f, 0.f, 0.f, 0.f);
    if (node < n) own = unpack_h(hin[(size_t)node * 4 + q]);
    tl4[ln * 5 + q] = own;
    __syncthreads();
#pragma unroll 4
    for (int i = 0; i < 16; ++i) {
      float tv = tl[ln * 20 + i];
#pragma unroll
      for (int c = 0; c < 4; ++c) {
        float4 wv = W0l[i * 16 + 4 * q + c];
        a[c].x = fmaf(tv, wv.x, a[c].x); a[c].y = fmaf(tv, wv.y, a[c].y);
        a[c].z = fmaf(tv, wv.z, a[c].z); a[c].w = fmaf(tv, wv.w, a[c].w);
      }
    }
  }
  if (node >= n) return;

  if (LAST) {
#pragma unroll
    for (int c = 0; c < 4; ++c) {
      float4 b = bias4[4 * q + c];
      a[c].x += b.x; a[c].y += b.y; a[c].z += b.z; a[c].w += b.w;
      a[c].x = (a[c].x >= 0.f) ? a[c].x : 0.01f * a[c].x;
      a[c].y = (a[c].y >= 0.f) ? a[c].y : 0.01f * a[c].y;
      a[c].z = (a[c].z >= 0.f) ? a[c].z : 0.01f * a[c].z;
      a[c].w = (a[c].w >= 0.f) ? a[c].w : 0.01f * a[c].w;
      outbuf[(size_t)node * 16 + 4 * q + c] = pack_h(a[c]);
    }
  } else {
#pragma unroll
    for (int c = 0; c < 4; ++c) acch[(size_t)node * 16 + 4 * q + c] = pack_h(a[c]);
  }
}

extern "C" void kernel_launch(void* const* d_in, const int* in_sizes, int n_in,
                              void* d_out, int out_size, void* d_ws, size_t ws_size,
                              hipStream_t stream) {
  const float* x    = (const float*)d_in[0];
  const int*   ei   = (const int*)d_in[1];
  const float* ew   = (const float*)d_in[2];
  const float* W1   = (const float*)d_in[4];
  const float* b1   = (const float*)d_in[5];
  const float* W2   = (const float*)d_in[6];
  const float* b2   = (const float*)d_in[7];
  const float* Wout = (const float*)d_in[8];
  const float* bout = (const float*)d_in[9];
  float* out = (float*)d_out;

  const int N = in_sizes[0] / 16;
  const int E = in_sizes[2];
  const int* src = ei;
  const int* dst = ei + E;

  const int NBLK = 256;                      // persistent blocks for hist/scatter
  const int CH = (E + NBLK - 1) / NBLK;      // edges per block
  const int NB = (N + 127) >> 7;             // coarse buckets (<=1024 for N<=131072)
  const int HN = NB * NBLK;                  // hist entries (multiple of 256)

  char* ws = (char*)d_ws;
  size_t off = 0;
  auto alloc = [&](size_t bytes) {
    char* p = ws + off;
    off = (off + bytes + 255) & ~(size_t)255;
    return p;
  };
  u32*     H      = (u32*)alloc((size_t)HN * 4);             // (bucket,block) hist/bases
  u32*     bsum   = (u32*)alloc(4096);
  float*   dinv   = (float*)alloc((size_t)N * 4);
  int*     ptr    = (int*)alloc(((size_t)N + 1) * 4);
  u64*     sorted = (u64*)alloc((size_t)E * 8);              // [w_f32|dstlow7|src17]
  u32*     ep     = (u32*)alloc((size_t)E * 4);              // packed 4B edges
  ushort4* xh     = (ushort4*)alloc((size_t)N * 16 * 2);     // N x 16 fp16
  ushort4* hb0    = (ushort4*)alloc((size_t)N * 64 * 2);     // t ping
  ushort4* hb1    = (ushort4*)alloc((size_t)N * 64 * 2);     // t pong
  ushort4* hb2    = (ushort4*)alloc((size_t)N * 64 * 2);     // layer outputs
  ushort4* acch   = (ushort4*)alloc((size_t)N * 64 * 2);     // fp16 acc (layer1/fallback)

  // ---- atomic-free CSR build ----
  k_hist<<<NBLK, 256, 0, stream>>>(dst, H, E, CH, NB, (const float4*)x, xh, N * 4);
  scanH_blocks<<<HN / 256, 256, 0, stream>>>(H, bsum, HN);
  scanH_sums<<<1, 1024, 0, stream>>>(bsum, HN / 256);
  scanH_add<<<HN / 256, 256, 0, stream>>>(H, bsum, HN);
  k_scatter<<<NBLK, 256, 0, stream>>>(src, dst, ew, H, sorted, E, CH, NB);
  k_bucket<<<NB, 256, 0, stream>>>(sorted, H, NBLK, ptr, dinv, N, E, NB);
  k_pack<<<NB, 256, 0, stream>>>(sorted, dinv, H, NBLK, ep, E, NB);

  int g4  = (N * 4 + 255) / 256;   // layer-1 fused (4 lanes/node)
  int g16 = (N * 16 + 255) / 256;  // fallback F=64 fused

  auto W1k = [&](int k) { return (const float4*)(W1 + (size_t)k * 1024); };
  auto W2k = [&](int l, int k) { return (const float4*)(W2 + ((size_t)l * 5 + k) * 4096); };

  // ---- Layer 1 (16 -> 64): acc in acch, t ping-pong hb0/hb1, h1 -> hb2 ----
  ptag16_k<true,  false><<<g4, 256, 0, stream>>>(ptr, ep, xh,  hb0, W1k(1), W1k(0), acch, nullptr, nullptr, N);
  ptag16_k<false, false><<<g4, 256, 0, stream>>>(ptr, ep, hb0, hb1, W1k(2), nullptr, acch, nullptr, nullptr, N);
  ptag16_k<false, false><<<g4, 256, 0, stream>>>(ptr, ep, hb1, hb0, W1k(3), nullptr, acch, nullptr, nullptr, N);
  ptag16_k<false, true ><<<g4, 256, 0, stream>>>(ptr, ep, hb0, nullptr, W1k(4), nullptr, acch,
                                                 (const float4*)b1, hb2, N);

  // ---- Layers 2+3 + head: persistent cooperative kernel (occupancy-gated) ----
  int maxB4 = 0, maxB5 = 0, maxB7 = 0;
  (void)hipOccupancyMaxActiveBlocksPerMultiprocessor(&maxB4, mega_k<4>, 256, 0);
  (void)hipOccupancyMaxActiveBlocksPerMultiprocessor(&maxB5, mega_k<5>, 256, 0);
  (void)hipOccupancyMaxActiveBlocksPerMultiprocessor(&maxB7, mega_k<7>, 256, 0);
  void* fn = nullptr;
  int grid = 0;
  if ((long)maxB4 * 256 * 16 * 4 >= (long)N) {
    fn = (void*)mega_k<4>; grid = maxB4 * 256;
  } else if ((long)maxB5 * 256 * 16 * 5 >= (long)N) {
    fn = (void*)mega_k<5>; grid = maxB5 * 256;
  } else if ((long)maxB7 * 256 * 16 * 7 >= (long)N) {
    fn = (void*)mega_k<7>; grid = maxB7 * 256;
  }

  if (fn) {
    const int* ptrA = ptr; const u32* epA = ep;
    ushort4 *h0A = hb0, *h1A = hb1, *h2A = hb2;
    const float *W2A = W2, *b2A = b2, *WoA = Wout, *boA = bout;
    float* outA = out; int nA = N;
    void* args[] = {&ptrA, &epA, &h0A, &h1A, &h2A, &W2A, &b2A, &WoA, &boA, &outA, &nA};
    hipLaunchCooperativeKernel(fn, dim3(grid), dim3(256), args, 0, stream);
  } else {
    // fallback: R10's proven dispatch sequence
    ptag64_k<true,  false, false><<<g16, 256, 0, stream>>>(ptr, ep, hb2, hb0, W2k(0,1), W2k(0,0), acch,
                                                           nullptr, nullptr, nullptr, nullptr, N);
    ptag64_k<false, false, false><<<g16, 256, 0, stream>>>(ptr, ep, hb0, hb1, W2k(0,2), nullptr, acch,
                                                           nullptr, nullptr, nullptr, nullptr, N);
    ptag64_k<false, false, false><<<g16, 256, 0, stream>>>(ptr, ep, hb1, hb0, W2k(0,3), nullptr, acch,
                                                           nullptr, nullptr, nullptr, nullptr, N);
    ptag64_k<false, true,  false><<<g16, 256, 0, stream>>>(ptr, ep, hb0, hb2, W2k(0,4), nullptr, acch,
                                                           (const float4*)b2, nullptr, nullptr, nullptr, N);
    ptag64_k<true,  false, false><<<g16, 256, 0, stream>>>(ptr, ep, hb2, hb0, W2k(1,1), W2k(1,0), acch,
                                                           nullptr, nullptr, nullptr, nullptr, N);
    ptag64_k<false, false, false><<<g16, 256, 0, stream>>>(ptr, ep, hb0, hb1, W2k(1,2), nullptr, acch,
                                                           nullptr, nullptr, nullptr, nullptr, N);
    ptag64_k<false, false, false><<<g16, 256, 0, stream>>>(ptr, ep, hb1, hb0, W2k(1,3), nullptr, acch,
                                                           nullptr, nullptr, nullptr, nullptr, N);
    ptag64_k<false, true,  true ><<<g16, 256, 0, stream>>>(ptr, ep, hb0, nullptr, W2k(1,4), nullptr, acch,
                                                           (const float4*)(b2 + 64), Wout, bout, out, N);
  }
}

// Round 4
// 953.647 us; speedup vs baseline: 1.2443x; 1.0495x over previous
//
#include <hip/hip_runtime.h>
#include <hip/hip_cooperative_groups.h>

namespace cg = cooperative_groups;

// ---------------------------------------------------------------------------
// TAGCN node regression: 3 TAGConv layers (K=4) + linear head, fp32 math.
// R14: zero-global-atomic CSR build (two-level bucket sort).
// R15: 4-edge quad software-pipelined gather (102->91us per ptag64).
// R16: octet-split gather for F=64: per node, 2 octets of 8 lanes each take
// alternating edge-quads; each lane covers 8 features via ONE 16B load.
// Per-edge replicated overhead (ep decode + addressing) halves (16->8 lanes);
// 32-bit voffset addressing. Partials recombined via 8x shfl_xor(8,16);
// lane (o,f8) owns float4-group g=2f8+o for tile/hout (mm_acc unchanged).
// KNOWN: mega_k coop path never runs (occupancy API accounts LDS vs 64KiB);
// ptag64 fallback is the real execution path. Gate fix deferred.
// ---------------------------------------------------------------------------

typedef unsigned long long u64;
typedef unsigned int u32;

__device__ __forceinline__ float h2f(unsigned short u) {
  _Float16 h;
  __builtin_memcpy(&h, &u, 2);
  return (float)h;
}
__device__ __forceinline__ unsigned short f2h(float f) {
  _Float16 h = (_Float16)f;  // RNE
  unsigned short u;
  __builtin_memcpy(&u, &h, 2);
  return u;
}
__device__ __forceinline__ ushort4 pack_h(float4 v) {
  ushort4 r;
  r.x = f2h(v.x); r.y = f2h(v.y); r.z = f2h(v.z); r.w = f2h(v.w);
  return r;
}
__device__ __forceinline__ float4 unpack_h(ushort4 u) {
  return make_float4(h2f(u.x), h2f(u.y), h2f(u.z), h2f(u.w));
}
// packed edge: [norm15 | src17]
__device__ __forceinline__ void dec_ep(u32 u, int& s, float& w) {
  s = (int)(u & 0x1FFFFu);
  w = h2f((unsigned short)(u >> 17));
}

// ---------------- atomic-free CSR build ----------------
// coarse bucket = dst >> 7 (128 nodes/bucket). NB <= 1024 (N <= 131072).
// item u64 = [0:8][w_f32:32][dst_low7:7][src:17]

// per-block LDS hist of dst>>7 -> H[bucket*NBLK + blk]; fused x->fp16
__global__ __launch_bounds__(256) void k_hist(const int* __restrict__ dst, u32* __restrict__ H,
                                              int E, int CH, int NB,
                                              const float4* __restrict__ x4,
                                              ushort4* __restrict__ xh, int n4) {
  __shared__ u32 hc[1024];
  int tid = threadIdx.x, blk = blockIdx.x, nblk = gridDim.x;
  for (int i = tid; i < 1024; i += 256) hc[i] = 0;
  for (int i = blk * 256 + tid; i < n4; i += nblk * 256) xh[i] = pack_h(x4[i]);
  __syncthreads();
  int e0 = blk * CH, e1 = min(E, e0 + CH);
  for (int e = e0 + tid; e < e1; e += 256) atomicAdd(&hc[((u32)dst[e]) >> 7], 1u);
  __syncthreads();
  for (int c = tid; c < NB; c += 256) H[(size_t)c * nblk + blk] = hc[c];
}

// exclusive scan of H (n = NB*256 entries), 256/block
__global__ void scanH_blocks(u32* __restrict__ H, u32* __restrict__ bsum, int n) {
  __shared__ u32 s[256];
  int tid = threadIdx.x;
  int i = blockIdx.x * 256 + tid;
  u32 v = (i < n) ? H[i] : 0;
  s[tid] = v;
  __syncthreads();
#pragma unroll
  for (int off = 1; off < 256; off <<= 1) {
    u32 t = (tid >= off) ? s[tid - off] : 0;
    __syncthreads();
    s[tid] += t;
    __syncthreads();
  }
  if (i < n) H[i] = s[tid] - v;
  if (tid == 255) bsum[blockIdx.x] = s[255];
}

__global__ void scanH_sums(u32* __restrict__ bsum, int nb) {
  __shared__ u32 s[1024];
  int tid = threadIdx.x;
  u32 v = (tid < nb) ? bsum[tid] : 0;
  s[tid] = v;
  __syncthreads();
#pragma unroll
  for (int off = 1; off < 1024; off <<= 1) {
    u32 t = (tid >= off) ? s[tid - off] : 0;
    __syncthreads();
    s[tid] += t;
    __syncthreads();
  }
  if (tid < nb) bsum[tid] = s[tid] - v;
}

__global__ void scanH_add(u32* __restrict__ H, const u32* __restrict__ bsum, int n) {
  int i = blockIdx.x * blockDim.x + threadIdx.x;
  if (i < n) H[i] += bsum[i >> 8];
}

// scatter edges into coarse-bucket regions via LDS cursors (no global atomics)
__global__ __launch_bounds__(256) void k_scatter(const int* __restrict__ src,
                                                 const int* __restrict__ dst,
                                                 const float* __restrict__ w,
                                                 const u32* __restrict__ H,
                                                 u64* __restrict__ sorted, int E, int CH, int NB) {
  __shared__ u32 cur[1024];
  int tid = threadIdx.x, blk = blockIdx.x, nblk = gridDim.x;
  for (int c = tid; c < NB; c += 256) cur[c] = H[(size_t)c * nblk + blk];
  __syncthreads();
  int e0 = blk * CH, e1 = min(E, e0 + CH);
  for (int e = e0 + tid; e < e1; e += 256) {
    int d = dst[e];
    int c = ((u32)d) >> 7;
    u32 p = atomicAdd(&cur[c], 1u);
    u64 it = (u64)(u32)src[e] | ((u64)((u32)d & 127u) << 17) |
             ((u64)__float_as_uint(w[e]) << 24);
    sorted[p] = it;
  }
}

// per-bucket: LDS stage -> 128-bin hist -> ptr/dinv -> in-place node reorder
#define BCAP 6144
__global__ __launch_bounds__(256) void k_bucket(u64* __restrict__ sorted,
                                                const u32* __restrict__ H, int NBLK,
                                                int* __restrict__ ptr, float* __restrict__ dinv,
                                                int N, int E, int NB) {
  __shared__ u64 stage[BCAP];
  __shared__ u32 cnt[128], base[128], cur[128], tmp[128];
  __shared__ float ws[128];
  int c = blockIdx.x, tid = threadIdx.x;
  int b0 = (int)H[(size_t)c * NBLK];
  int b1 = (c + 1 < NB) ? (int)H[(size_t)(c + 1) * NBLK] : E;
  int m = b1 - b0;
  if (tid < 128) { cnt[tid] = 0; ws[tid] = 0.f; }
  __syncthreads();
  for (int i = tid; i < m; i += 256) {
    u64 it = sorted[b0 + i];
    stage[i] = it;
    int lo = (int)((it >> 17) & 127u);
    atomicAdd(&cnt[lo], 1u);
    atomicAdd(&ws[lo], __uint_as_float((u32)(it >> 24)));
  }
  __syncthreads();
  // exclusive scan of cnt[0..127]
  u32 v = (tid < 128) ? cnt[tid] : 0;
  if (tid < 128) tmp[tid] = v;
  __syncthreads();
#pragma unroll
  for (int off = 1; off < 128; off <<= 1) {
    u32 t = 0;
    if (tid < 128 && tid >= off) t = tmp[tid - off];
    __syncthreads();
    if (tid < 128) tmp[tid] += t;
    __syncthreads();
  }
  if (tid < 128) {
    base[tid] = tmp[tid] - v;
    cur[tid] = tmp[tid] - v;
    int node = c * 128 + tid;
    if (node < N) {
      ptr[node] = b0 + (int)base[tid];
      float d = ws[tid];
      dinv[node] = (d > 0.f) ? rsqrtf(fmaxf(d, 1e-30f)) : 0.f;
    }
  }
  if (c == NB - 1 && tid == 0) ptr[N] = E;
  __syncthreads();
  for (int i = tid; i < m; i += 256) {
    u64 it = stage[i];
    int lo = (int)((it >> 17) & 127u);
    u32 p = atomicAdd(&cur[lo], 1u);
    sorted[b0 + (int)p] = it;
  }
}

// norm fixup -> packed ep [norm15|src17]; dst reconstructed from bucket id
__global__ __launch_bounds__(256) void k_pack(const u64* __restrict__ sorted,
                                              const float* __restrict__ dinv,
                                              const u32* __restrict__ H, int NBLK,
                                              u32* __restrict__ ep, int E, int NB) {
  int c = blockIdx.x;
  int b0 = (int)H[(size_t)c * NBLK];
  int b1 = (c + 1 < NB) ? (int)H[(size_t)(c + 1) * NBLK] : E;
  for (int i = b0 + threadIdx.x; i < b1; i += 256) {
    u64 it = sorted[i];
    int s = (int)(it & 0x1FFFFu);
    int dn = c * 128 + (int)((it >> 17) & 127u);
    float wv = __uint_as_float((u32)(it >> 24));
    float nv = dinv[s] * wv * dinv[dn];
    ep[i] = ((u32)f2h(nv) << 17) | (u32)s;
  }
}

// ---- R15 gather (4-edge quads, pipelined): used by ptag16 and mega_k ----
__device__ __forceinline__ void acc_e(float4& a, u32 pe, ushort4 h) {
  float w = h2f((unsigned short)(pe >> 17));
  a.x = fmaf(w, h2f(h.x), a.x); a.y = fmaf(w, h2f(h.y), a.y);
  a.z = fmaf(w, h2f(h.z), a.z); a.w = fmaf(w, h2f(h.w), a.w);
}

template <int F4>
__device__ __forceinline__ float4 gather(const int* __restrict__ ptr, const u32* __restrict__ ep,
                                         const ushort4* __restrict__ hin, int node, int f4) {
  int e0 = ptr[node], e1 = ptr[node + 1];
  float4 a = make_float4(0.f, 0.f, 0.f, 0.f);
  int e = e0;
  // head: align to 4-edge (16B) boundary
  while (e < e1 && (e & 3)) {
    u32 pe = ep[e];
    acc_e(a, pe, hin[(u32)(pe & 0x1FFFFu) * F4 + f4]);
    ++e;
  }
  int nq = (e1 - e) >> 2;
  if (nq > 0) {
    uint4 p = *(const uint4*)(ep + e);
    ushort4 h0 = hin[(u32)(p.x & 0x1FFFFu) * F4 + f4];
    ushort4 h1 = hin[(u32)(p.y & 0x1FFFFu) * F4 + f4];
    ushort4 h2 = hin[(u32)(p.z & 0x1FFFFu) * F4 + f4];
    ushort4 h3 = hin[(u32)(p.w & 0x1FFFFu) * F4 + f4];
    for (int q = 1; q < nq; ++q) {
      uint4 pn = *(const uint4*)(ep + e + 4 * q);   // next quad's edges
      ushort4 g0 = hin[(u32)(pn.x & 0x1FFFFu) * F4 + f4];
      ushort4 g1 = hin[(u32)(pn.y & 0x1FFFFu) * F4 + f4];
      ushort4 g2 = hin[(u32)(pn.z & 0x1FFFFu) * F4 + f4];
      ushort4 g3 = hin[(u32)(pn.w & 0x1FFFFu) * F4 + f4];
      acc_e(a, p.x, h0); acc_e(a, p.y, h1);         // FMAs on current quad
      acc_e(a, p.z, h2); acc_e(a, p.w, h3);         // (loads above in flight)
      p = pn; h0 = g0; h1 = g1; h2 = g2; h3 = g3;
    }
    acc_e(a, p.x, h0); acc_e(a, p.y, h1);
    acc_e(a, p.z, h2); acc_e(a, p.w, h3);
    e += nq * 4;
  }
  // tail
  while (e < e1) {
    u32 pe = ep[e];
    acc_e(a, pe, hin[(u32)(pe & 0x1FFFFu) * F4 + f4]);
    ++e;
  }
  return a;
}

// ---- R16 octet gather, F=64: 8 lanes x 8 features (16B rows) ----
__device__ __forceinline__ void acc8(float4& a0, float4& a1, u32 pe, uint4 r) {
  float w = h2f((unsigned short)(pe >> 17));
  a0.x = fmaf(w, h2f((unsigned short)(r.x & 0xFFFFu)), a0.x);
  a0.y = fmaf(w, h2f((unsigned short)(r.x >> 16)), a0.y);
  a0.z = fmaf(w, h2f((unsigned short)(r.y & 0xFFFFu)), a0.z);
  a0.w = fmaf(w, h2f((unsigned short)(r.y >> 16)), a0.w);
  a1.x = fmaf(w, h2f((unsigned short)(r.z & 0xFFFFu)), a1.x);
  a1.y = fmaf(w, h2f((unsigned short)(r.z >> 16)), a1.y);
  a1.z = fmaf(w, h2f((unsigned short)(r.w & 0xFFFFu)), a1.z);
  a1.w = fmaf(w, h2f((unsigned short)(r.w >> 16)), a1.w);
}

// octet o in {0,1} of a 16-lane node group; lane covers features [8*f8, 8*f8+8).
// Octet o takes quads with (q&1)==o and head/tail edges with (e&1)==o.
__device__ __forceinline__ void gather64o(const int* __restrict__ ptr, const u32* __restrict__ ep,
                                          const ushort4* __restrict__ hin, int node,
                                          int f8, int o, float4& a0, float4& a1) {
  int e0 = ptr[node], e1 = ptr[node + 1];
  const u32 foff = 2u * (u32)f8;   // ushort4 offset within row
  int e = e0;
  while (e < e1 && (e & 3)) {
    if ((e & 1) == o) {
      u32 pe = ep[e];
      uint4 r = *(const uint4*)(hin + ((u32)(pe & 0x1FFFFu) * 16u + foff));
      acc8(a0, a1, pe, r);
    }
    ++e;
  }
  int nq = (e1 - e) >> 2;
  int q = o;
  if (q < nq) {
    uint4 p = *(const uint4*)(ep + e + 4 * q);
    uint4 r0 = *(const uint4*)(hin + ((u32)(p.x & 0x1FFFFu) * 16u + foff));
    uint4 r1 = *(const uint4*)(hin + ((u32)(p.y & 0x1FFFFu) * 16u + foff));
    for (;;) {
      uint4 r2 = *(const uint4*)(hin + ((u32)(p.z & 0x1FFFFu) * 16u + foff));
      uint4 r3 = *(const uint4*)(hin + ((u32)(p.w & 0x1FFFFu) * 16u + foff));
      acc8(a0, a1, p.x, r0);
      acc8(a0, a1, p.y, r1);
      int qn = q + 2;
      if (qn >= nq) {
        acc8(a0, a1, p.z, r2);
        acc8(a0, a1, p.w, r3);
        break;
      }
      uint4 pn = *(const uint4*)(ep + e + 4 * qn);
      r0 = *(const uint4*)(hin + ((u32)(pn.x & 0x1FFFFu) * 16u + foff));
      r1 = *(const uint4*)(hin + ((u32)(pn.y & 0x1FFFFu) * 16u + foff));
      acc8(a0, a1, p.z, r2);
      acc8(a0, a1, p.w, r3);
      p = pn; q = qn;
    }
  }
  e += nq * 4;
  while (e < e1) {
    if ((e & 1) == o) {
      u32 pe = ep[e];
      uint4 r = *(const uint4*)(hin + ((u32)(pe & 0x1FFFFu) * 16u + foff));
      acc8(a0, a1, pe, r);
    }
    ++e;
  }
}

// scalar-broadcast mm accumulate: a += t(slot ln) @ W  (R6's 28-VGPR shape).
// t element i of slot ln lives at word ln*64 + (((i>>2)^ln)<<2 | (i&3)).
// Tile rows are WAVE-PRIVATE (ln = tid>>4): same-wave LDS RAW needs no barrier.
__device__ __forceinline__ void mm_acc(const float* __restrict__ tl, const float4* __restrict__ Wl,
                                       int ln, int j4, float4& a) {
#pragma unroll 8
  for (int i = 0; i < 64; ++i) {
    float tv = tl[ln * 64 + ((((i >> 2) ^ ln) << 2) | (i & 3))];
    float4 wv = Wl[i * 16 + j4];
    a.x = fmaf(tv, wv.x, a.x); a.y = fmaf(tv, wv.y, a.y);
    a.z = fmaf(tv, wv.z, a.z); a.w = fmaf(tv, wv.w, a.w);
  }
}

// ---------- persistent cooperative kernel: layers 2+3 + head ----------
template <int NC>
__global__ __launch_bounds__(256) void mega_k(
    const int* __restrict__ ptr, const u32* __restrict__ ep,
    ushort4* __restrict__ hb0, ushort4* __restrict__ hb1, ushort4* __restrict__ hb2,
    const float* __restrict__ W2, const float* __restrict__ b2,
    const float* __restrict__ Wout, const float* __restrict__ bout,
    float* __restrict__ outv, int n) {
  cg::grid_group grid = cg::this_grid();
  __shared__ float4 Wl[1024];
  __shared__ float4 tl4[256];
  const float* tl = (const float*)tl4;
  const int tid = threadIdx.x, j4 = tid & 15, ln = tid >> 4;
  const int nb = (int)gridDim.x;
  float4 acc[NC];

  for (int L = 0; L < 2; ++L) {
    const float* WL = W2 + (size_t)L * 5 * 4096;
#pragma unroll
    for (int c = 0; c < NC; ++c) acc[c] = make_float4(0.f, 0.f, 0.f, 0.f);

    // ---- own-term pass: acc += h_in @ W0  (h_in = hb2 for both layers) ----
    {
      const float4* W04 = (const float4*)WL;
      for (int i = tid; i < 1024; i += 256) Wl[i] = W04[i];
      __syncthreads();
#pragma unroll
      for (int c = 0; c < NC; ++c) {
        int node = (c * nb + (int)blockIdx.x) * 16 + ln;
        float4 own = make_float4(0.f, 0.f, 0.f, 0.f);
        if (node < n) own = unpack_h(hb2[(size_t)node * 16 + j4]);
        tl4[ln * 16 + (j4 ^ ln)] = own;   // wave-private row, no barrier
        mm_acc(tl, Wl, ln, j4, acc[c]);
      }
      __syncthreads();
    }

    // ---- k = 1..4 propagation phases ----
    for (int k = 1; k <= 4; ++k) {
      const ushort4* gsrc = (k == 1) ? hb2 : ((k == 3) ? hb1 : hb0);
      ushort4* gdst = (k == 2) ? hb1 : hb0;
      const bool last = (k == 4);
      const float4* Wk4 = (const float4*)(WL + (size_t)k * 4096);
      for (int i = tid; i < 1024; i += 256) Wl[i] = Wk4[i];
      __syncthreads();
#pragma unroll
      for (int c = 0; c < NC; ++c) {
        int node = (c * nb + (int)blockIdx.x) * 16 + ln;
        float4 t = make_float4(0.f, 0.f, 0.f, 0.f);
        if (node < n) {
          t = gather<16>(ptr, ep, gsrc, node, j4);
          if (!last) gdst[(size_t)node * 16 + j4] = pack_h(t);
        }
        tl4[ln * 16 + (j4 ^ ln)] = t;     // wave-private, no barrier
        mm_acc(tl, Wl, ln, j4, acc[c]);
      }
      if (last) {  // epilogue: bias + leaky -> layer output (L0) or head (L1)
        const float4* bias4 = (const float4*)(b2 + (size_t)L * 64);
#pragma unroll
        for (int c = 0; c < NC; ++c) {
          int node = (c * nb + (int)blockIdx.x) * 16 + ln;
          if (node >= n) continue;
          float4 a = acc[c];
          float4 b = bias4[j4];
          a.x += b.x; a.y += b.y; a.z += b.z; a.w += b.w;
          a.x = (a.x >= 0.f) ? a.x : 0.01f * a.x;
          a.y = (a.y >= 0.f) ? a.y : 0.01f * a.y;
          a.z = (a.z >= 0.f) ? a.z : 0.01f * a.z;
          a.w = (a.w >= 0.f) ? a.w : 0.01f * a.w;
          if (L == 0) {
            hb2[(size_t)node * 16 + j4] = pack_h(a);
          } else {
            float v = a.x * Wout[4 * j4] + a.y * Wout[4 * j4 + 1] +
                      a.z * Wout[4 * j4 + 2] + a.w * Wout[4 * j4 + 3];
            v += __shfl_down(v, 8, 16);
            v += __shfl_down(v, 4, 16);
            v += __shfl_down(v, 2, 16);
            v += __shfl_down(v, 1, 16);
            if (j4 == 0) outv[node] = v + bout[0];
          }
        }
      }
      if (!(L == 1 && k == 4)) {
        __threadfence();  // device-scope release of gdst/hb2 stores
        grid.sync();      // phase boundary (covers block sync for Wl reload)
      }
    }
  }
}

// ---------- fallback fused prop + matmul, F=64 (R16 octet gather) ----------
template <bool FIRST, bool LAST, bool HEAD>
__launch_bounds__(256)
__global__ void ptag64_k(const int* __restrict__ ptr, const u32* __restrict__ ep,
                         const ushort4* __restrict__ hin, ushort4* __restrict__ hout,
                         const float4* __restrict__ Wk4, const float4* __restrict__ W04,
                         ushort4* __restrict__ acch, const float4* __restrict__ bias4,
                         const float* __restrict__ Wout, const float* __restrict__ bout,
                         float* __restrict__ outv, int n) {
  __shared__ float4 Wl[1024];
  __shared__ float4 tl4[256];
  const float* tl = (const float*)tl4;
  int tid = threadIdx.x;
  for (int i = tid; i < 1024; i += 256) Wl[i] = Wk4[i];
  int gid = blockIdx.x * 256 + tid;
  int node = gid >> 4, j4 = gid & 15, ln = tid >> 4;
  const int o = j4 >> 3, f8 = j4 & 7;

  float4 a0 = make_float4(0.f, 0.f, 0.f, 0.f);
  float4 a1 = make_float4(0.f, 0.f, 0.f, 0.f);
  if (node < n) gather64o(ptr, ep, hin, node, f8, o, a0, a1);
  // cross-octet combine: partner lane is j4^8 within the 16-lane group
  a0.x += __shfl_xor(a0.x, 8, 16); a0.y += __shfl_xor(a0.y, 8, 16);
  a0.z += __shfl_xor(a0.z, 8, 16); a0.w += __shfl_xor(a0.w, 8, 16);
  a1.x += __shfl_xor(a1.x, 8, 16); a1.y += __shfl_xor(a1.y, 8, 16);
  a1.z += __shfl_xor(a1.z, 8, 16); a1.w += __shfl_xor(a1.w, 8, 16);
  // lane (o,f8) owns float4-group g = 2*f8+o (features 8*f8+4*o ..+4)
  float4 t = (o == 0) ? a0 : a1;
  int g = 2 * f8 + o;
  if (node < n && !LAST) hout[(size_t)node * 16 + g] = pack_h(t);
  tl4[ln * 16 + (g ^ ln)] = t;
  __syncthreads();

  float4 a = make_float4(0.f, 0.f, 0.f, 0.f);
  if (!FIRST && node < n) a = unpack_h(acch[(size_t)node * 16 + j4]);
  mm_acc(tl, Wl, ln, j4, a);
  if (FIRST) {
    __syncthreads();
    for (int i = tid; i < 1024; i += 256) Wl[i] = W04[i];
    float4 own = make_float4(0.f, 0.f, 0.f, 0.f);
    if (node < n) own = unpack_h(hin[(size_t)node * 16 + j4]);
    tl4[ln * 16 + (j4 ^ ln)] = own;
    __syncthreads();
    mm_acc(tl, Wl, ln, j4, a);
  }
  if (node >= n) return;

  if (LAST) {
    float4 b = bias4[j4];
    a.x += b.x; a.y += b.y; a.z += b.z; a.w += b.w;
    a.x = (a.x >= 0.f) ? a.x : 0.01f * a.x;
    a.y = (a.y >= 0.f) ? a.y : 0.01f * a.y;
    a.z = (a.z >= 0.f) ? a.z : 0.01f * a.z;
    a.w = (a.w >= 0.f) ? a.w : 0.01f * a.w;
    if (HEAD) {
      float v = a.x * Wout[4 * j4] + a.y * Wout[4 * j4 + 1] +
                a.z * Wout[4 * j4 + 2] + a.w * Wout[4 * j4 + 3];
      v += __shfl_down(v, 8, 16);
      v += __shfl_down(v, 4, 16);
      v += __shfl_down(v, 2, 16);
      v += __shfl_down(v, 1, 16);
      if (j4 == 0) outv[node] = v + bout[0];
    } else {
      hout[(size_t)node * 16 + j4] = pack_h(a);
    }
  } else {
    acch[(size_t)node * 16 + j4] = pack_h(a);
  }
}

// ---------- fused prop + matmul, layer 1: F_in=16 (4 lanes/node) ----------
template <bool FIRST, bool LAST>
__launch_bounds__(256)
__global__ void ptag16_k(const int* __restrict__ ptr, const u32* __restrict__ ep,
                         const ushort4* __restrict__ hin, ushort4* __restrict__ hout,
                         const float4* __restrict__ Wk4, const float4* __restrict__ W04,
                         ushort4* __restrict__ acch, const float4* __restrict__ bias4,
                         ushort4* __restrict__ outbuf, int n) {
  __shared__ float4 Wl[256];
  __shared__ float4 W0l[FIRST ? 256 : 1];
  __shared__ float4 tl4[64 * 5];
  const float* tl = (const float*)tl4;
  int tid = threadIdx.x;
  Wl[tid] = Wk4[tid];
  if (FIRST) W0l[tid] = W04[tid];
  int gid = blockIdx.x * 256 + tid;
  int node = gid >> 2, q = tid & 3, ln = tid >> 2;

  float4 t = make_float4(0.f, 0.f, 0.f, 0.f);
  if (node < n) {
    t = gather<4>(ptr, ep, hin, node, q);
    if (!LAST) hout[(size_t)node * 4 + q] = pack_h(t);
  }
  tl4[ln * 5 + q] = t;
  __syncthreads();

  float4 a[4];
#pragma unroll
  for (int c = 0; c < 4; ++c) a[c] = make_float4(0.f, 0.f, 0.f, 0.f);
  if (!FIRST && node < n) {
#pragma unroll
    for (int c = 0; c < 4; ++c) a[c] = unpack_h(acch[(size_t)node * 16 + 4 * q + c]);
  }
#pragma unroll 4
  for (int i = 0; i < 16; ++i) {
    float tv = tl[ln * 20 + i];
#pragma unroll
    for (int c = 0; c < 4; ++c) {
      float4 wv = Wl[i * 16 + 4 * q + c];
      a[c].x = fmaf(tv, wv.x, a[c].x); a[c].y = fmaf(tv, wv.y, a[c].y);
      a[c].z = fmaf(tv, wv.z, a[c].z); a[c].w = fmaf(tv, wv.w, a[c].w);
    }
  }
  if (FIRST) {
    __syncthreads();
    float4 own = make_float4(0.f, 0.f, 0.f, 0.f);
    if (node < n) own = unpack_h(hin[(size_t)node * 4 + q]);
    tl4[ln * 5 + q] = own;
    __syncthreads();
#pragma unroll 4
    for (int i = 0; i < 16; ++i) {
      float tv = tl[ln * 20 + i];
#pragma unroll
      for (int c = 0; c < 4; ++c) {
        float4 wv = W0l[i * 16 + 4 * q + c];
        a[c].x = fmaf(tv, wv.x, a[c].x); a[c].y = fmaf(tv, wv.y, a[c].y);
        a[c].z = fmaf(tv, wv.z, a[c].z); a[c].w = fmaf(tv, wv.w, a[c].w);
      }
    }
  }
  if (node >= n) return;

  if (LAST) {
#pragma unroll
    for (int c = 0; c < 4; ++c) {
      float4 b = bias4[4 * q + c];
      a[c].x += b.x; a[c].y += b.y; a[c].z += b.z; a[c].w += b.w;
      a[c].x = (a[c].x >= 0.f) ? a[c].x : 0.01f * a[c].x;
      a[c].y = (a[c].y >= 0.f) ? a[c].y : 0.01f * a[c].y;
      a[c].z = (a[c].z >= 0.f) ? a[c].z : 0.01f * a[c].z;
      a[c].w = (a[c].w >= 0.f) ? a[c].w : 0.01f * a[c].w;
      outbuf[(size_t)node * 16 + 4 * q + c] = pack_h(a[c]);
    }
  } else {
#pragma unroll
    for (int c = 0; c < 4; ++c) acch[(size_t)node * 16 + 4 * q + c] = pack_h(a[c]);
  }
}

extern "C" void kernel_launch(void* const* d_in, const int* in_sizes, int n_in,
                              void* d_out, int out_size, void* d_ws, size_t ws_size,
                              hipStream_t stream) {
  const float* x    = (const float*)d_in[0];
  const int*   ei   = (const int*)d_in[1];
  const float* ew   = (const float*)d_in[2];
  const float* W1   = (const float*)d_in[4];
  const float* b1   = (const float*)d_in[5];
  const float* W2   = (const float*)d_in[6];
  const float* b2   = (const float*)d_in[7];
  const float* Wout = (const float*)d_in[8];
  const float* bout = (const float*)d_in[9];
  float* out = (float*)d_out;

  const int N = in_sizes[0] / 16;
  const int E = in_sizes[2];
  const int* src = ei;
  const int* dst = ei + E;

  const int NBLK = 256;                      // persistent blocks for hist/scatter
  const int CH = (E + NBLK - 1) / NBLK;      // edges per block
  const int NB = (N + 127) >> 7;             // coarse buckets (<=1024 for N<=131072)
  const int HN = NB * NBLK;                  // hist entries (multiple of 256)

  char* ws = (char*)d_ws;
  size_t off = 0;
  auto alloc = [&](size_t bytes) {
    char* p = ws + off;
    off = (off + bytes + 255) & ~(size_t)255;
    return p;
  };
  u32*     H      = (u32*)alloc((size_t)HN * 4);             // (bucket,block) hist/bases
  u32*     bsum   = (u32*)alloc(4096);
  float*   dinv   = (float*)alloc((size_t)N * 4);
  int*     ptr    = (int*)alloc(((size_t)N + 1) * 4);
  u64*     sorted = (u64*)alloc((size_t)E * 8);              // [w_f32|dstlow7|src17]
  u32*     ep     = (u32*)alloc((size_t)E * 4);              // packed 4B edges
  ushort4* xh     = (ushort4*)alloc((size_t)N * 16 * 2);     // N x 16 fp16
  ushort4* hb0    = (ushort4*)alloc((size_t)N * 64 * 2);     // t ping
  ushort4* hb1    = (ushort4*)alloc((size_t)N * 64 * 2);     // t pong
  ushort4* hb2    = (ushort4*)alloc((size_t)N * 64 * 2);     // layer outputs
  ushort4* acch   = (ushort4*)alloc((size_t)N * 64 * 2);     // fp16 acc (layer1/fallback)

  // ---- atomic-free CSR build ----
  k_hist<<<NBLK, 256, 0, stream>>>(dst, H, E, CH, NB, (const float4*)x, xh, N * 4);
  scanH_blocks<<<HN / 256, 256, 0, stream>>>(H, bsum, HN);
  scanH_sums<<<1, 1024, 0, stream>>>(bsum, HN / 256);
  scanH_add<<<HN / 256, 256, 0, stream>>>(H, bsum, HN);
  k_scatter<<<NBLK, 256, 0, stream>>>(src, dst, ew, H, sorted, E, CH, NB);
  k_bucket<<<NB, 256, 0, stream>>>(sorted, H, NBLK, ptr, dinv, N, E, NB);
  k_pack<<<NB, 256, 0, stream>>>(sorted, dinv, H, NBLK, ep, E, NB);

  int g4  = (N * 4 + 255) / 256;   // layer-1 fused (4 lanes/node)
  int g16 = (N * 16 + 255) / 256;  // fallback F=64 fused

  auto W1k = [&](int k) { return (const float4*)(W1 + (size_t)k * 1024); };
  auto W2k = [&](int l, int k) { return (const float4*)(W2 + ((size_t)l * 5 + k) * 4096); };

  // ---- Layer 1 (16 -> 64): acc in acch, t ping-pong hb0/hb1, h1 -> hb2 ----
  ptag16_k<true,  false><<<g4, 256, 0, stream>>>(ptr, ep, xh,  hb0, W1k(1), W1k(0), acch, nullptr, nullptr, N);
  ptag16_k<false, false><<<g4, 256, 0, stream>>>(ptr, ep, hb0, hb1, W1k(2), nullptr, acch, nullptr, nullptr, N);
  ptag16_k<false, false><<<g4, 256, 0, stream>>>(ptr, ep, hb1, hb0, W1k(3), nullptr, acch, nullptr, nullptr, N);
  ptag16_k<false, true ><<<g4, 256, 0, stream>>>(ptr, ep, hb0, nullptr, W1k(4), nullptr, acch,
                                                 (const float4*)b1, hb2, N);

  // ---- Layers 2+3 + head: persistent cooperative kernel (occupancy-gated) ----
  int maxB4 = 0, maxB5 = 0, maxB7 = 0;
  (void)hipOccupancyMaxActiveBlocksPerMultiprocessor(&maxB4, mega_k<4>, 256, 0);
  (void)hipOccupancyMaxActiveBlocksPerMultiprocessor(&maxB5, mega_k<5>, 256, 0);
  (void)hipOccupancyMaxActiveBlocksPerMultiprocessor(&maxB7, mega_k<7>, 256, 0);
  void* fn = nullptr;
  int grid = 0;
  if ((long)maxB4 * 256 * 16 * 4 >= (long)N) {
    fn = (void*)mega_k<4>; grid = maxB4 * 256;
  } else if ((long)maxB5 * 256 * 16 * 5 >= (long)N) {
    fn = (void*)mega_k<5>; grid = maxB5 * 256;
  } else if ((long)maxB7 * 256 * 16 * 7 >= (long)N) {
    fn = (void*)mega_k<7>; grid = maxB7 * 256;
  }

  if (fn) {
    const int* ptrA = ptr; const u32* epA = ep;
    ushort4 *h0A = hb0, *h1A = hb1, *h2A = hb2;
    const float *W2A = W2, *b2A = b2, *WoA = Wout, *boA = bout;
    float* outA = out; int nA = N;
    void* args[] = {&ptrA, &epA, &h0A, &h1A, &h2A, &W2A, &b2A, &WoA, &boA, &outA, &nA};
    hipLaunchCooperativeKernel(fn, dim3(grid), dim3(256), args, 0, stream);
  } else {
    // fallback: R10's proven dispatch sequence
    ptag64_k<true,  false, false><<<g16, 256, 0, stream>>>(ptr, ep, hb2, hb0, W2k(0,1), W2k(0,0), acch,
                                                           nullptr, nullptr, nullptr, nullptr, N);
    ptag64_k<false, false, false><<<g16, 256, 0, stream>>>(ptr, ep, hb0, hb1, W2k(0,2), nullptr, acch,
                                                           nullptr, nullptr, nullptr, nullptr, N);
    ptag64_k<false, false, false><<<g16, 256, 0, stream>>>(ptr, ep, hb1, hb0, W2k(0,3), nullptr, acch,
                                                           nullptr, nullptr, nullptr, nullptr, N);
    ptag64_k<false, true,  false><<<g16, 256, 0, stream>>>(ptr, ep, hb0, hb2, W2k(0,4), nullptr, acch,
                                                           (const float4*)b2, nullptr, nullptr, nullptr, N);
    ptag64_k<true,  false, false><<<g16, 256, 0, stream>>>(ptr, ep, hb2, hb0, W2k(1,1), W2k(1,0), acch,
                                                           nullptr, nullptr, nullptr, nullptr, N);
    ptag64_k<false, false, false><<<g16, 256, 0, stream>>>(ptr, ep, hb0, hb1, W2k(1,2), nullptr, acch,
                                                           nullptr, nullptr, nullptr, nullptr, N);
    ptag64_k<false, false, false><<<g16, 256, 0, stream>>>(ptr, ep, hb1, hb0, W2k(1,3), nullptr, acch,
                                                           nullptr, nullptr, nullptr, nullptr, N);
    ptag64_k<false, true,  true ><<<g16, 256, 0, stream>>>(ptr, ep, hb0, nullptr, W2k(1,4), nullptr, acch,
                                                           (const float4*)(b2 + 64), Wout, bout, out, N);
  }
}